// Round 8
// baseline (2625.737 us; speedup 1.0000x reference)
//
#include <hip/hip_runtime.h>

typedef unsigned short u16;
typedef __attribute__((ext_vector_type(8))) short bf16x8;
typedef __attribute__((ext_vector_type(4))) float f32x4;

#define TOK  8192
#define HD   2048
#define FFD  8192
#define NEXP 4
#define CAPE 4352   // per-expert padded row capacity (E[Mv]=4096, sigma~45, +5.7σ)

#define S_BARRIER() asm volatile("s_barrier" ::: "memory")
#define VMCNT(n)    asm volatile("s_waitcnt vmcnt(" #n ")" ::: "memory")

__device__ __forceinline__ u16 f2bf(float f){
  unsigned u = __float_as_uint(f);
  u += 0x7fffu + ((u >> 16) & 1u);
  return (u16)(u >> 16);
}

__device__ __forceinline__ float gelu_tanh(float x){
  float u = 0.7978845608028654f * (x + 0.044715f * x * x * x);
  return 0.5f * x * (1.0f + tanhf(u));
}

__device__ __forceinline__ void gload_lds16(const void* g, void* l){
  __builtin_amdgcn_global_load_lds((const __attribute__((address_space(1))) void*)g,
                                   (__attribute__((address_space(3))) void*)l, 16, 0, 0);
}

__device__ __forceinline__ f32x4 mfma_bf16(bf16x8 a, bf16x8 b, f32x4 c){
  asm("v_mfma_f32_16x16x32_bf16 %0, %1, %2, %0" : "+v"(c) : "v"(a), "v"(b));
  return c;
}

// ---------------- conversions ----------------
__global__ __launch_bounds__(256) void cvt_to_bf16(const float* __restrict__ in,
                                                   u16* __restrict__ out, int n4){
  int i = blockIdx.x * 256 + threadIdx.x;
  if (i >= n4) return;
  float4 v = ((const float4*)in)[i];
  ushort4 o;
  o.x = f2bf(v.x); o.y = f2bf(v.y); o.z = f2bf(v.z); o.w = f2bf(v.w);
  ((ushort4*)out)[i] = o;
}

// in [R][C] f32  ->  out [C][R] bf16   (R3-proven version)
__global__ __launch_bounds__(256) void transpose_cvt(const float* __restrict__ in,
                                                     u16* __restrict__ out, int R, int C){
  __shared__ float tile[64][65];
  int tx = threadIdx.x & 63;
  int ty = threadIdx.x >> 6;
  size_t r0 = (size_t)blockIdx.y * 64;
  size_t c0 = (size_t)blockIdx.x * 64;
  #pragma unroll
  for (int i = ty; i < 64; i += 4)
    tile[i][tx] = in[(r0 + i) * C + (c0 + tx)];
  __syncthreads();
  #pragma unroll
  for (int i = ty; i < 64; i += 4)
    out[(c0 + i) * R + (r0 + tx)] = f2bf(tile[tx][i]);
}

// ---------------- router ----------------
__global__ __launch_bounds__(256) void router_kernel(
    const float* __restrict__ X, const float* __restrict__ wg, const float* __restrict__ bg,
    float* __restrict__ probs, int* __restrict__ topi, float* __restrict__ gatew){
  int t = blockIdx.x;
  const float* x = X + (size_t)t * HD;
  float a0 = 0.f, a1 = 0.f, a2 = 0.f, a3 = 0.f;
  for (int h = threadIdx.x; h < HD; h += 256){
    float xv = x[h];
    float4 w = ((const float4*)wg)[h];
    a0 += xv * w.x; a1 += xv * w.y; a2 += xv * w.z; a3 += xv * w.w;
  }
  __shared__ float red[4][256];
  red[0][threadIdx.x] = a0; red[1][threadIdx.x] = a1;
  red[2][threadIdx.x] = a2; red[3][threadIdx.x] = a3;
  __syncthreads();
  for (int s = 128; s > 0; s >>= 1){
    if (threadIdx.x < (unsigned)s){
      #pragma unroll
      for (int e = 0; e < 4; e++) red[e][threadIdx.x] += red[e][threadIdx.x + s];
    }
    __syncthreads();
  }
  if (threadIdx.x == 0){
    float l[4], p[4];
    #pragma unroll
    for (int e = 0; e < 4; e++) l[e] = red[e][0] + bg[e];
    float mx = fmaxf(fmaxf(l[0], l[1]), fmaxf(l[2], l[3]));
    float s = 0.f;
    #pragma unroll
    for (int e = 0; e < 4; e++){ p[e] = expf(l[e] - mx); s += p[e]; }
    #pragma unroll
    for (int e = 0; e < 4; e++){ p[e] /= s; probs[t * 4 + e] = p[e]; }
    int e0 = 0;
    for (int e = 1; e < 4; e++) if (p[e] > p[e0]) e0 = e;
    int e1 = -1;
    for (int e = 0; e < 4; e++){ if (e == e0) continue; if (e1 < 0 || p[e] > p[e1]) e1 = e; }
    float g = p[e0] + p[e1];
    topi[t * 2] = e0; topi[t * 2 + 1] = e1;
    #pragma unroll
    for (int e = 0; e < 4; e++)
      gatew[(size_t)e * TOK + t] = (e == e0) ? p[e0] / g : (e == e1) ? p[e1] / g : 0.f;
  }
}

// ---------------- expert token lists ----------------
__global__ __launch_bounds__(256) void build_lists(const int* __restrict__ topi,
                                                   int* __restrict__ cnt,
                                                   int* __restrict__ lists){
  int t = blockIdx.x * 256 + threadIdx.x;
  if (t >= TOK) return;
  #pragma unroll
  for (int k = 0; k < 2; k++){
    int e = topi[t * 2 + k];
    int p = atomicAdd(cnt + e, 1);
    lists[e * TOK + p] = t;
  }
}

// ---------------- aux loss ----------------
__global__ __launch_bounds__(256) void aux_kernel(const float* __restrict__ probs,
                                                  const int* __restrict__ topi,
                                                  float* __restrict__ out_aux){
  __shared__ float sp[4][256];
  __shared__ float sc[4][256];
  float p[4] = {0,0,0,0}, c[4] = {0,0,0,0};
  for (int t = threadIdx.x; t < TOK; t += 256){
    #pragma unroll
    for (int e = 0; e < 4; e++) p[e] += probs[t * 4 + e];
    c[topi[t * 2]]     += 1.f;
    c[topi[t * 2 + 1]] += 1.f;
  }
  #pragma unroll
  for (int e = 0; e < 4; e++){ sp[e][threadIdx.x] = p[e]; sc[e][threadIdx.x] = c[e]; }
  __syncthreads();
  for (int s = 128; s > 0; s >>= 1){
    if (threadIdx.x < (unsigned)s){
      #pragma unroll
      for (int e = 0; e < 4; e++){
        sp[e][threadIdx.x] += sp[e][threadIdx.x + s];
        sc[e][threadIdx.x] += sc[e][threadIdx.x + s];
      }
    }
    __syncthreads();
  }
  if (threadIdx.x == 0){
    float aux = 0.f;
    #pragma unroll
    for (int e = 0; e < 4; e++)
      aux += (sc[e][0] / (float)(TOK * 2)) * (sp[e][0] / (float)TOK);
    *out_aux = 4.f * aux;
  }
}

// =====================================================================
// GEMM1: 256x256 tile, BK=64, 512 thr (8 waves 2x4, wave-tile 128x64),
// 8-phase (4/tile) counted-vmcnt pipeline, st-swizzled LDS, A gathered.
// =====================================================================
__global__ __launch_bounds__(512, 2) void gemm1_8p(
    const u16* __restrict__ Xb, const u16* __restrict__ BT,
    const int* __restrict__ rowidx, const int* __restrict__ cntp,
    const float* __restrict__ bias, u16* __restrict__ Hout)
{
  __shared__ __align__(16) u16 As[2 * 256 * 64];   // 64 KB
  __shared__ __align__(16) u16 Bs[2 * 256 * 64];   // 64 KB
  const int Mv = *cntp;
  const int nwg = gridDim.x * gridDim.y;
  const int orig = blockIdx.x + gridDim.x * blockIdx.y;
  const int q8 = nwg >> 3, r8 = nwg & 7, xcd = orig & 7, rank = orig >> 3;
  const int v = (xcd < r8 ? xcd * (q8 + 1) : r8 * (q8 + 1) + (xcd - r8) * q8) + rank;
  const int by = v % (int)gridDim.y, bx = v / (int)gridDim.y;
  const int browg = by * 256;
  if (browg >= Mv) return;
  const size_t bcol = (size_t)bx * 256;

  const int tid = threadIdx.x, lane = tid & 63, w = tid >> 6;
  const int wr = w >> 2, wc = w & 3;
  const int l8 = lane >> 3;
  const int csw  = ((lane & 7) ^ l8) * 8;          // stage-src col swizzle (elems)
  const int sw   = (lane & 7) * 8;
  const int h8   = ((lane >> 4) & 3) * 8;
  const int colk0 = h8 ^ sw, colk1 = (32 | h8) ^ sw; // ds_read col swizzle
  const int r16 = lane & 15;

  const u16* bsrc[4]; int bch[4];
  #pragma unroll
  for (int j = 0; j < 4; j++){
    int rb = wc * 64 + wr * 32 + j * 8;
    bch[j] = rb * 128;
    bsrc[j] = BT + (bcol + rb + l8) * (size_t)HD + csw;
  }
  const u16* asrc[4]; int ach[4];
  #pragma unroll
  for (int q = 0; q < 4; q++){
    int rb = wr * 128 + q * 32 + wc * 8;
    ach[q] = rb * 128;
    int rl = browg + rb + l8; if (rl > Mv - 1) rl = Mv - 1;
    asrc[q] = Xb + (size_t)rowidx[rl] * HD + csw;
  }

  f32x4 acc[8][4];
  #pragma unroll
  for (int m = 0; m < 8; m++)
    #pragma unroll
    for (int n = 0; n < 4; n++) acc[m][n] = (f32x4){0.f, 0.f, 0.f, 0.f};
  bf16x8 bC[8];

  const int NT = HD / 64;  // 32
  #pragma unroll
  for (int j = 0; j < 4; j++) gload_lds16(bsrc[j], (char*)Bs + bch[j]);
  #pragma unroll
  for (int q = 0; q < 4; q++) gload_lds16(asrc[q], (char*)As + ach[q]);
  VMCNT(3); S_BARRIER();

  for (int t = 0; t < NT; ++t){
    const u16* asb = As + (t & 1) * 16384;
    const u16* bsb = Bs + (t & 1) * 16384;
    char* anb = (char*)As + ((t & 1) ^ 1) * 32768;
    char* bnb = (char*)Bs + ((t & 1) ^ 1) * 32768;
    const size_t ko = (size_t)(t + 1) * 64;
    const bool lastT = (t == NT - 1);
    #pragma unroll 4
    for (int p = 0; p < 4; p++){
      if (p == 0){
        #pragma unroll
        for (int nf = 0; nf < 4; nf++){
          const u16* bp = bsb + (wc * 64 + nf * 16 + r16) * 64;
          bC[nf * 2]     = *(const bf16x8*)(bp + colk0);
          bC[nf * 2 + 1] = *(const bf16x8*)(bp + colk1);
        }
      }
      bf16x8 a[2][2];
      #pragma unroll
      for (int mi = 0; mi < 2; mi++){
        const u16* ap = asb + (wr * 128 + (2 * p + mi) * 16 + r16) * 64;
        a[mi][0] = *(const bf16x8*)(ap + colk0);
        a[mi][1] = *(const bf16x8*)(ap + colk1);
      }
      if (!lastT){
        if      (p == 0){ gload_lds16(bsrc[0] + ko, bnb + bch[0]); gload_lds16(bsrc[1] + ko, bnb + bch[1]); }
        else if (p == 1){ gload_lds16(bsrc[2] + ko, bnb + bch[2]); gload_lds16(bsrc[3] + ko, bnb + bch[3]); }
        else if (p == 2){ gload_lds16(asrc[0] + ko, anb + ach[0]); gload_lds16(asrc[1] + ko, anb + ach[1]); }
        else            { gload_lds16(asrc[2] + ko, anb + ach[2]); gload_lds16(asrc[3] + ko, anb + ach[3]); }
      }
      S_BARRIER();
      __builtin_amdgcn_s_setprio(1);
      #pragma unroll
      for (int mi = 0; mi < 2; mi++)
        #pragma unroll
        for (int nf = 0; nf < 4; nf++){
          acc[2 * p + mi][nf] = mfma_bf16(a[mi][0], bC[nf * 2],     acc[2 * p + mi][nf]);
          acc[2 * p + mi][nf] = mfma_bf16(a[mi][1], bC[nf * 2 + 1], acc[2 * p + mi][nf]);
        }
      __builtin_amdgcn_s_setprio(0);
      if (!lastT){ if (p == 0) VMCNT(4); else if (p == 1) VMCNT(5); else if (p == 2) VMCNT(6); else VMCNT(3); }
      else       { if (p == 0) VMCNT(2); else if (p == 1) VMCNT(1); else if (p == 2) VMCNT(0); }
      S_BARRIER();
    }
  }

  const int cl = r16, rg = (lane >> 4) * 4;
  const size_t c0 = bcol + wc * 64;
  float bv[4];
  #pragma unroll
  for (int nf = 0; nf < 4; nf++) bv[nf] = bias[c0 + nf * 16 + cl];
  #pragma unroll
  for (int mf = 0; mf < 8; mf++){
    const size_t rb = (size_t)(browg + wr * 128 + mf * 16 + rg);
    #pragma unroll
    for (int nf = 0; nf < 4; nf++){
      const size_t col = c0 + nf * 16 + cl;
      #pragma unroll
      for (int j = 0; j < 4; j++)
        Hout[(rb + j) * FFD + col] = f2bf(gelu_tanh(acc[mf][nf][j] + bv[nf]));
    }
  }
}

// =====================================================================
// GEMM2: 128x128 tile, BK=64, 256 thr (4 waves 2x2, wave-tile 64x64).
// R7->R8: 4-slot LDS ring (128 KB), 2-tile-deep prefetch: tile t issues
// t+3's 8 loads; end-of-tile waits vmcnt(16) (drains t+1) + 1 barrier.
// Issue-to-wait ~2 tiles (~600+cyc) vs R7's ~0. 1 vmcnt + 1 barrier/tile.
// out[tok] += gate[tok]*(H @ W2T^T + b2)
// =====================================================================
__global__ __launch_bounds__(256) void gemm2_r4(
    const u16* __restrict__ Hb, const u16* __restrict__ BT,
    const int* __restrict__ rowidx, const int* __restrict__ cntp,
    const float* __restrict__ bias, const float* __restrict__ gate,
    float* __restrict__ Cout)
{
  __shared__ __align__(16) u16 As[4 * 128 * 64];   // 64 KB, 4 slots x 16 KB
  __shared__ __align__(16) u16 Bs[4 * 128 * 64];   // 64 KB
  const int Mv = *cntp;
  const int nwg = gridDim.x * gridDim.y;
  const int orig = blockIdx.x + gridDim.x * blockIdx.y;
  const int q8 = nwg >> 3, r8 = nwg & 7, xcd = orig & 7, rank = orig >> 3;
  const int v = (xcd < r8 ? xcd * (q8 + 1) : r8 * (q8 + 1) + (xcd - r8) * q8) + rank;
  const int bx = v % (int)gridDim.x, by = v / (int)gridDim.x;   // y-major: A-band hot
  const int browg = by * 128;
  if (browg >= Mv) return;
  const size_t bcol = (size_t)bx * 128;

  const int tid = threadIdx.x, lane = tid & 63, w = tid >> 6;   // 4 waves 2x2
  const int wr = w >> 1, wc = w & 1;
  const int l8 = lane >> 3;
  const int csw  = ((lane & 7) ^ l8) * 8;
  const int sw   = (lane & 7) * 8;
  const int h8   = ((lane >> 4) & 3) * 8;
  const int colk0 = h8 ^ sw, colk1 = (32 | h8) ^ sw;
  const int r16 = lane & 15;

  // B ops j=0..3: rows j*32 + w*8 + l8 (covers 128 jointly over waves)
  const u16* bsrc[4]; int bch[4];
  #pragma unroll
  for (int j = 0; j < 4; j++){
    int rb = j * 32 + w * 8;
    bch[j] = rb * 128;
    bsrc[j] = BT + (bcol + rb + l8) * (size_t)FFD + csw;
  }
  // A ops q=0..3: rows wr*64 + q*16 + wc*8 + l8 (covers 128 jointly)
  const u16* asrc[4]; int ach[4];
  #pragma unroll
  for (int q = 0; q < 4; q++){
    int rb = wr * 64 + q * 16 + wc * 8;
    ach[q] = rb * 128;
    asrc[q] = Hb + (size_t)(browg + rb + l8) * FFD + csw;
  }

  f32x4 acc[4][4];
  #pragma unroll
  for (int m = 0; m < 4; m++)
    #pragma unroll
    for (int n = 0; n < 4; n++) acc[m][n] = (f32x4){0.f, 0.f, 0.f, 0.f};
  bf16x8 bC[8];

  const int NT = FFD / 64;  // 128 (divisible by 4)

  // prologue: stage tiles 0,1,2 into slots 0,1,2 (24 loads); tile0 done -> vmcnt(16)
  #pragma unroll
  for (int tt = 0; tt < 3; tt++){
    const size_t ko = (size_t)tt * 64;
    char* bs = (char*)Bs + tt * 16384;
    char* as = (char*)As + tt * 16384;
    #pragma unroll
    for (int j = 0; j < 4; j++) gload_lds16(bsrc[j] + ko, bs + bch[j]);
    #pragma unroll
    for (int q = 0; q < 4; q++) gload_lds16(asrc[q] + ko, as + ach[q]);
  }
  VMCNT(16); S_BARRIER();

  for (int t = 0; t < NT; ++t){
    const u16* asb = As + (t & 3) * 8192;   // 8192 u16 = 16 KB per slot
    const u16* bsb = Bs + (t & 3) * 8192;

    // B frags + A m0,m1 from slot t&3
    #pragma unroll
    for (int nf = 0; nf < 4; nf++){
      const u16* bp = bsb + (wc * 64 + nf * 16 + r16) * 64;
      bC[nf * 2]     = *(const bf16x8*)(bp + colk0);
      bC[nf * 2 + 1] = *(const bf16x8*)(bp + colk1);
    }
    bf16x8 a01[2][2];
    #pragma unroll
    for (int mi = 0; mi < 2; mi++){
      const u16* ap = asb + (wr * 64 + mi * 16 + r16) * 64;
      a01[mi][0] = *(const bf16x8*)(ap + colk0);
      a01[mi][1] = *(const bf16x8*)(ap + colk1);
    }

    // issue tile t+3 into slot (t+3)&3 (that slot's last reader was tile t-1,
    // whose reads finished before the barrier at end of tile t-1)
    if (t < NT - 3){
      const size_t ko = (size_t)(t + 3) * 64;
      char* bs = (char*)Bs + ((t + 3) & 3) * 16384;
      char* as = (char*)As + ((t + 3) & 3) * 16384;
      #pragma unroll
      for (int j = 0; j < 4; j++) gload_lds16(bsrc[j] + ko, bs + bch[j]);
      #pragma unroll
      for (int q = 0; q < 4; q++) gload_lds16(asrc[q] + ko, as + ach[q]);
    }

    __builtin_amdgcn_s_setprio(1);
    #pragma unroll
    for (int mi = 0; mi < 2; mi++)
      #pragma unroll
      for (int nf = 0; nf < 4; nf++){
        acc[mi][nf] = mfma_bf16(a01[mi][0], bC[nf * 2],     acc[mi][nf]);
        acc[mi][nf] = mfma_bf16(a01[mi][1], bC[nf * 2 + 1], acc[mi][nf]);
      }
    __builtin_amdgcn_s_setprio(0);

    // A m2,m3 + MFMA
    bf16x8 a23[2][2];
    #pragma unroll
    for (int mi = 0; mi < 2; mi++){
      const u16* ap = asb + (wr * 64 + (2 + mi) * 16 + r16) * 64;
      a23[mi][0] = *(const bf16x8*)(ap + colk0);
      a23[mi][1] = *(const bf16x8*)(ap + colk1);
    }
    __builtin_amdgcn_s_setprio(1);
    #pragma unroll
    for (int mi = 0; mi < 2; mi++)
      #pragma unroll
      for (int nf = 0; nf < 4; nf++){
        acc[2 + mi][nf] = mfma_bf16(a23[mi][0], bC[nf * 2],     acc[2 + mi][nf]);
        acc[2 + mi][nf] = mfma_bf16(a23[mi][1], bC[nf * 2 + 1], acc[2 + mi][nf]);
      }
    __builtin_amdgcn_s_setprio(0);

    // tile boundary: ensure tile t+1 resident; keep t+2 (and t+3) in flight
    if      (t < NT - 3) VMCNT(16);
    else if (t == NT - 3) VMCNT(8);
    else if (t == NT - 2) VMCNT(0);
    S_BARRIER();
  }

  // epilogue: scatter-add (serialized expert dispatches + unique tokens -> race-free)
  const int cl = r16, rg = (lane >> 4) * 4;
  const size_t c0 = bcol + wc * 64;
  float bv[4];
  #pragma unroll
  for (int nf = 0; nf < 4; nf++) bv[nf] = bias[c0 + nf * 16 + cl];
  #pragma unroll
  for (int mf = 0; mf < 4; mf++){
    const int rbase = browg + wr * 64 + mf * 16 + rg;
    int   tok[4]; float gv[4];
    #pragma unroll
    for (int j = 0; j < 4; j++){
      const bool ok = (rbase + j) < Mv;
      tok[j] = ok ? rowidx[rbase + j] : -1;
      gv[j]  = ok ? gate[tok[j]] : 0.f;
    }
    #pragma unroll
    for (int nf = 0; nf < 4; nf++){
      const size_t col = c0 + nf * 16 + cl;
      #pragma unroll
      for (int j = 0; j < 4; j++){
        if (tok[j] >= 0){
          const size_t idx = (size_t)tok[j] * HD + col;
          Cout[idx] += gv[j] * (acc[mf][nf][j] + bv[nf]);
        }
      }
    }
  }
}

// ---------------- host ----------------
extern "C" void kernel_launch(void* const* d_in, const int* in_sizes, int n_in,
                              void* d_out, int out_size, void* d_ws, size_t ws_size,
                              hipStream_t stream){
  (void)in_sizes; (void)n_in; (void)ws_size;
  const float* X  = (const float*)d_in[0];
  const float* wg = (const float*)d_in[1];
  const float* bg = (const float*)d_in[2];
  const float* w1 = (const float*)d_in[3];
  const float* b1 = (const float*)d_in[4];
  const float* w2 = (const float*)d_in[5];
  const float* b2 = (const float*)d_in[6];
  float* out = (float*)d_out;

  char* ws = (char*)d_ws;
  size_t off = 0;
  auto alloc = [&](size_t b) -> char* {
    char* p = ws + off;
    off = (off + b + 255) & ~(size_t)255;
    return p;
  };
  u16*   Xb    = (u16*)  alloc((size_t)TOK * HD * 2);
  u16*   W1T   = (u16*)  alloc((size_t)FFD * HD * 2);
  u16*   W2T   = (u16*)  alloc((size_t)HD * FFD * 2);
  float* probs = (float*)alloc((size_t)TOK * 4 * 4);
  int*   topi  = (int*)  alloc((size_t)TOK * 2 * 4);
  float* gatew = (float*)alloc((size_t)NEXP * TOK * 4);
  int*   cnt   = (int*)  alloc((size_t)NEXP * 4);
  int*   lists = (int*)  alloc((size_t)NEXP * TOK * 4);
  u16*   Hb    = (u16*)  alloc((size_t)CAPE * FFD * 2);   // 68 MB

  hipMemsetAsync(cnt, 0, NEXP * sizeof(int), stream);
  hipMemsetAsync(out, 0, (size_t)TOK * HD * sizeof(float), stream);

  cvt_to_bf16<<<(TOK * HD / 4 + 255) / 256, 256, 0, stream>>>(X, Xb, TOK * HD / 4);
  router_kernel<<<TOK, 256, 0, stream>>>(X, wg, bg, probs, topi, gatew);
  build_lists<<<TOK / 256, 256, 0, stream>>>(topi, cnt, lists);
  aux_kernel<<<1, 256, 0, stream>>>(probs, topi, out + (out_size - 1));

  for (int e = 0; e < NEXP; ++e){
    transpose_cvt<<<dim3(FFD / 64, HD / 64), 256, 0, stream>>>(
        w1 + (size_t)e * HD * FFD, W1T, HD, FFD);
    transpose_cvt<<<dim3(HD / 64, FFD / 64), 256, 0, stream>>>(
        w2 + (size_t)e * FFD * HD, W2T, FFD, HD);
    gemm1_8p<<<dim3(FFD / 256, CAPE / 256), 512, 0, stream>>>(
        Xb, W1T, lists + e * TOK, cnt + e, b1 + (size_t)e * FFD, Hb);
    gemm2_r4<<<dim3(HD / 128, CAPE / 128), 256, 0, stream>>>(
        Hb, W2T, lists + e * TOK, cnt + e, b2 + (size_t)e * HD,
        gatew + (size_t)e * TOK, out);
  }
}

// Round 10
// 2206.805 us; speedup vs baseline: 1.1898x; 1.1898x over previous
//
#include <hip/hip_runtime.h>

typedef unsigned short u16;
typedef __attribute__((ext_vector_type(8))) short bf16x8;
typedef __attribute__((ext_vector_type(4))) float f32x4;

#define TOK  8192
#define HD   2048
#define FFD  8192
#define NEXP 4
#define CAPE 4352   // per-expert padded row capacity (E[Mv]=4096, sigma~45, +5.7σ)

#define S_BARRIER() asm volatile("s_barrier" ::: "memory")
#define VMCNT(n)    asm volatile("s_waitcnt vmcnt(" #n ")" ::: "memory")

__device__ __forceinline__ u16 f2bf(float f){
  unsigned u = __float_as_uint(f);
  u += 0x7fffu + ((u >> 16) & 1u);
  return (u16)(u >> 16);
}

__device__ __forceinline__ float gelu_tanh(float x){
  float u = 0.7978845608028654f * (x + 0.044715f * x * x * x);
  return 0.5f * x * (1.0f + tanhf(u));
}

__device__ __forceinline__ void gload_lds16(const void* g, void* l){
  __builtin_amdgcn_global_load_lds((const __attribute__((address_space(1))) void*)g,
                                   (__attribute__((address_space(3))) void*)l, 16, 0, 0);
}

__device__ __forceinline__ f32x4 mfma_bf16(bf16x8 a, bf16x8 b, f32x4 c){
  asm("v_mfma_f32_16x16x32_bf16 %0, %1, %2, %0" : "+v"(c) : "v"(a), "v"(b));
  return c;
}

// ---------------- conversions ----------------
__global__ __launch_bounds__(256) void cvt_to_bf16(const float* __restrict__ in,
                                                   u16* __restrict__ out, int n4){
  int i = blockIdx.x * 256 + threadIdx.x;
  if (i >= n4) return;
  float4 v = ((const float4*)in)[i];
  ushort4 o;
  o.x = f2bf(v.x); o.y = f2bf(v.y); o.z = f2bf(v.z); o.w = f2bf(v.w);
  ((ushort4*)out)[i] = o;
}

// in [R][C] f32  ->  out [C][R] bf16   (R3-proven version)
__global__ __launch_bounds__(256) void transpose_cvt(const float* __restrict__ in,
                                                     u16* __restrict__ out, int R, int C){
  __shared__ float tile[64][65];
  int tx = threadIdx.x & 63;
  int ty = threadIdx.x >> 6;
  size_t r0 = (size_t)blockIdx.y * 64;
  size_t c0 = (size_t)blockIdx.x * 64;
  #pragma unroll
  for (int i = ty; i < 64; i += 4)
    tile[i][tx] = in[(r0 + i) * C + (c0 + tx)];
  __syncthreads();
  #pragma unroll
  for (int i = ty; i < 64; i += 4)
    out[(c0 + i) * R + (r0 + tx)] = f2bf(tile[tx][i]);
}

// ---------------- router ----------------
__global__ __launch_bounds__(256) void router_kernel(
    const float* __restrict__ X, const float* __restrict__ wg, const float* __restrict__ bg,
    float* __restrict__ probs, int* __restrict__ topi, float* __restrict__ gatew){
  int t = blockIdx.x;
  const float* x = X + (size_t)t * HD;
  float a0 = 0.f, a1 = 0.f, a2 = 0.f, a3 = 0.f;
  for (int h = threadIdx.x; h < HD; h += 256){
    float xv = x[h];
    float4 w = ((const float4*)wg)[h];
    a0 += xv * w.x; a1 += xv * w.y; a2 += xv * w.z; a3 += xv * w.w;
  }
  __shared__ float red[4][256];
  red[0][threadIdx.x] = a0; red[1][threadIdx.x] = a1;
  red[2][threadIdx.x] = a2; red[3][threadIdx.x] = a3;
  __syncthreads();
  for (int s = 128; s > 0; s >>= 1){
    if (threadIdx.x < (unsigned)s){
      #pragma unroll
      for (int e = 0; e < 4; e++) red[e][threadIdx.x] += red[e][threadIdx.x + s];
    }
    __syncthreads();
  }
  if (threadIdx.x == 0){
    float l[4], p[4];
    #pragma unroll
    for (int e = 0; e < 4; e++) l[e] = red[e][0] + bg[e];
    float mx = fmaxf(fmaxf(l[0], l[1]), fmaxf(l[2], l[3]));
    float s = 0.f;
    #pragma unroll
    for (int e = 0; e < 4; e++){ p[e] = expf(l[e] - mx); s += p[e]; }
    #pragma unroll
    for (int e = 0; e < 4; e++){ p[e] /= s; probs[t * 4 + e] = p[e]; }
    int e0 = 0;
    for (int e = 1; e < 4; e++) if (p[e] > p[e0]) e0 = e;
    int e1 = -1;
    for (int e = 0; e < 4; e++){ if (e == e0) continue; if (e1 < 0 || p[e] > p[e1]) e1 = e; }
    float g = p[e0] + p[e1];
    topi[t * 2] = e0; topi[t * 2 + 1] = e1;
    #pragma unroll
    for (int e = 0; e < 4; e++)
      gatew[(size_t)e * TOK + t] = (e == e0) ? p[e0] / g : (e == e1) ? p[e1] / g : 0.f;
  }
}

// ---------------- expert token lists ----------------
__global__ __launch_bounds__(256) void build_lists(const int* __restrict__ topi,
                                                   int* __restrict__ cnt,
                                                   int* __restrict__ lists){
  int t = blockIdx.x * 256 + threadIdx.x;
  if (t >= TOK) return;
  #pragma unroll
  for (int k = 0; k < 2; k++){
    int e = topi[t * 2 + k];
    int p = atomicAdd(cnt + e, 1);
    lists[e * TOK + p] = t;
  }
}

// ---------------- aux loss ----------------
__global__ __launch_bounds__(256) void aux_kernel(const float* __restrict__ probs,
                                                  const int* __restrict__ topi,
                                                  float* __restrict__ out_aux){
  __shared__ float sp[4][256];
  __shared__ float sc[4][256];
  float p[4] = {0,0,0,0}, c[4] = {0,0,0,0};
  for (int t = threadIdx.x; t < TOK; t += 256){
    #pragma unroll
    for (int e = 0; e < 4; e++) p[e] += probs[t * 4 + e];
    c[topi[t * 2]]     += 1.f;
    c[topi[t * 2 + 1]] += 1.f;
  }
  #pragma unroll
  for (int e = 0; e < 4; e++){ sp[e][threadIdx.x] = p[e]; sc[e][threadIdx.x] = c[e]; }
  __syncthreads();
  for (int s = 128; s > 0; s >>= 1){
    if (threadIdx.x < (unsigned)s){
      #pragma unroll
      for (int e = 0; e < 4; e++){
        sp[e][threadIdx.x] += sp[e][threadIdx.x + s];
        sc[e][threadIdx.x] += sc[e][threadIdx.x + s];
      }
    }
    __syncthreads();
  }
  if (threadIdx.x == 0){
    float aux = 0.f;
    #pragma unroll
    for (int e = 0; e < 4; e++)
      aux += (sc[e][0] / (float)(TOK * 2)) * (sp[e][0] / (float)TOK);
    *out_aux = 4.f * aux;
  }
}

// =====================================================================
// GEMM1: 256x256 tile, BK=64, 512 thr (8 waves 2x4, wave-tile 128x64),
// 8-phase (4/tile) counted-vmcnt pipeline, st-swizzled LDS, A gathered.
// =====================================================================
__global__ __launch_bounds__(512, 2) void gemm1_8p(
    const u16* __restrict__ Xb, const u16* __restrict__ BT,
    const int* __restrict__ rowidx, const int* __restrict__ cntp,
    const float* __restrict__ bias, u16* __restrict__ Hout)
{
  __shared__ __align__(16) u16 As[2 * 256 * 64];   // 64 KB
  __shared__ __align__(16) u16 Bs[2 * 256 * 64];   // 64 KB
  const int Mv = *cntp;
  const int nwg = gridDim.x * gridDim.y;
  const int orig = blockIdx.x + gridDim.x * blockIdx.y;
  const int q8 = nwg >> 3, r8 = nwg & 7, xcd = orig & 7, rank = orig >> 3;
  const int v = (xcd < r8 ? xcd * (q8 + 1) : r8 * (q8 + 1) + (xcd - r8) * q8) + rank;
  const int by = v % (int)gridDim.y, bx = v / (int)gridDim.y;
  const int browg = by * 256;
  if (browg >= Mv) return;
  const size_t bcol = (size_t)bx * 256;

  const int tid = threadIdx.x, lane = tid & 63, w = tid >> 6;
  const int wr = w >> 2, wc = w & 3;
  const int l8 = lane >> 3;
  const int csw  = ((lane & 7) ^ l8) * 8;          // stage-src col swizzle (elems)
  const int sw   = (lane & 7) * 8;
  const int h8   = ((lane >> 4) & 3) * 8;
  const int colk0 = h8 ^ sw, colk1 = (32 | h8) ^ sw; // ds_read col swizzle
  const int r16 = lane & 15;

  const u16* bsrc[4]; int bch[4];
  #pragma unroll
  for (int j = 0; j < 4; j++){
    int rb = wc * 64 + wr * 32 + j * 8;
    bch[j] = rb * 128;
    bsrc[j] = BT + (bcol + rb + l8) * (size_t)HD + csw;
  }
  const u16* asrc[4]; int ach[4];
  #pragma unroll
  for (int q = 0; q < 4; q++){
    int rb = wr * 128 + q * 32 + wc * 8;
    ach[q] = rb * 128;
    int rl = browg + rb + l8; if (rl > Mv - 1) rl = Mv - 1;
    asrc[q] = Xb + (size_t)rowidx[rl] * HD + csw;
  }

  f32x4 acc[8][4];
  #pragma unroll
  for (int m = 0; m < 8; m++)
    #pragma unroll
    for (int n = 0; n < 4; n++) acc[m][n] = (f32x4){0.f, 0.f, 0.f, 0.f};
  bf16x8 bC[8];

  const int NT = HD / 64;  // 32
  #pragma unroll
  for (int j = 0; j < 4; j++) gload_lds16(bsrc[j], (char*)Bs + bch[j]);
  #pragma unroll
  for (int q = 0; q < 4; q++) gload_lds16(asrc[q], (char*)As + ach[q]);
  VMCNT(3); S_BARRIER();

  for (int t = 0; t < NT; ++t){
    const u16* asb = As + (t & 1) * 16384;
    const u16* bsb = Bs + (t & 1) * 16384;
    char* anb = (char*)As + ((t & 1) ^ 1) * 32768;
    char* bnb = (char*)Bs + ((t & 1) ^ 1) * 32768;
    const size_t ko = (size_t)(t + 1) * 64;
    const bool lastT = (t == NT - 1);
    #pragma unroll 4
    for (int p = 0; p < 4; p++){
      if (p == 0){
        #pragma unroll
        for (int nf = 0; nf < 4; nf++){
          const u16* bp = bsb + (wc * 64 + nf * 16 + r16) * 64;
          bC[nf * 2]     = *(const bf16x8*)(bp + colk0);
          bC[nf * 2 + 1] = *(const bf16x8*)(bp + colk1);
        }
      }
      bf16x8 a[2][2];
      #pragma unroll
      for (int mi = 0; mi < 2; mi++){
        const u16* ap = asb + (wr * 128 + (2 * p + mi) * 16 + r16) * 64;
        a[mi][0] = *(const bf16x8*)(ap + colk0);
        a[mi][1] = *(const bf16x8*)(ap + colk1);
      }
      if (!lastT){
        if      (p == 0){ gload_lds16(bsrc[0] + ko, bnb + bch[0]); gload_lds16(bsrc[1] + ko, bnb + bch[1]); }
        else if (p == 1){ gload_lds16(bsrc[2] + ko, bnb + bch[2]); gload_lds16(bsrc[3] + ko, bnb + bch[3]); }
        else if (p == 2){ gload_lds16(asrc[0] + ko, anb + ach[0]); gload_lds16(asrc[1] + ko, anb + ach[1]); }
        else            { gload_lds16(asrc[2] + ko, anb + ach[2]); gload_lds16(asrc[3] + ko, anb + ach[3]); }
      }
      S_BARRIER();
      __builtin_amdgcn_s_setprio(1);
      #pragma unroll
      for (int mi = 0; mi < 2; mi++)
        #pragma unroll
        for (int nf = 0; nf < 4; nf++){
          acc[2 * p + mi][nf] = mfma_bf16(a[mi][0], bC[nf * 2],     acc[2 * p + mi][nf]);
          acc[2 * p + mi][nf] = mfma_bf16(a[mi][1], bC[nf * 2 + 1], acc[2 * p + mi][nf]);
        }
      __builtin_amdgcn_s_setprio(0);
      if (!lastT){ if (p == 0) VMCNT(4); else if (p == 1) VMCNT(5); else if (p == 2) VMCNT(6); else VMCNT(3); }
      else       { if (p == 0) VMCNT(2); else if (p == 1) VMCNT(1); else if (p == 2) VMCNT(0); }
      S_BARRIER();
    }
  }

  const int cl = r16, rg = (lane >> 4) * 4;
  const size_t c0 = bcol + wc * 64;
  float bv[4];
  #pragma unroll
  for (int nf = 0; nf < 4; nf++) bv[nf] = bias[c0 + nf * 16 + cl];
  #pragma unroll
  for (int mf = 0; mf < 8; mf++){
    const size_t rb = (size_t)(browg + wr * 128 + mf * 16 + rg);
    #pragma unroll
    for (int nf = 0; nf < 4; nf++){
      const size_t col = c0 + nf * 16 + cl;
      #pragma unroll
      for (int j = 0; j < 4; j++)
        Hout[(rb + j) * FFD + col] = f2bf(gelu_tanh(acc[mf][nf][j] + bv[nf]));
    }
  }
}

// =====================================================================
// GEMM2: 128x128 tile, BK=64, 256 thr (4 waves 2x2, wave-tile 64x64).
// R8->R9: A triple-buffer (48K) + B double-buffer (32K) = 80KB ->
// 2 blocks/CU kept; tile t issues B(t+1), A(t+2); end-of-tile
// vmcnt(4) drains A(t+1)+B(t+1), leaves A(t+2) in flight.
// A issue-to-wait = 2 tiles, B = 1 tile; 1 barrier + 1 vmcnt per tile.
// out[tok] += gate[tok]*(H @ W2T^T + b2)
// =====================================================================
__global__ __launch_bounds__(256, 2) void gemm2_tri(
    const u16* __restrict__ Hb, const u16* __restrict__ BT,
    const int* __restrict__ rowidx, const int* __restrict__ cntp,
    const float* __restrict__ bias, const float* __restrict__ gate,
    float* __restrict__ Cout)
{
  __shared__ __align__(16) u16 As[3 * 128 * 64];   // 48 KB, 3 slots
  __shared__ __align__(16) u16 Bs[2 * 128 * 64];   // 32 KB, 2 slots
  const int Mv = *cntp;
  const int nwg = gridDim.x * gridDim.y;
  const int orig = blockIdx.x + gridDim.x * blockIdx.y;
  const int q8 = nwg >> 3, r8 = nwg & 7, xcd = orig & 7, rank = orig >> 3;
  const int v = (xcd < r8 ? xcd * (q8 + 1) : r8 * (q8 + 1) + (xcd - r8) * q8) + rank;
  const int bx = v % (int)gridDim.x, by = v / (int)gridDim.x;   // y-major: A-band hot
  const int browg = by * 128;
  if (browg >= Mv) return;
  const size_t bcol = (size_t)bx * 128;

  const int tid = threadIdx.x, lane = tid & 63, w = tid >> 6;   // 4 waves 2x2
  const int wr = w >> 1, wc = w & 1;
  const int l8 = lane >> 3;
  const int csw  = ((lane & 7) ^ l8) * 8;
  const int sw   = (lane & 7) * 8;
  const int h8   = ((lane >> 4) & 3) * 8;
  const int colk0 = h8 ^ sw, colk1 = (32 | h8) ^ sw;
  const int r16 = lane & 15;

  // B ops j=0..3: rows j*32 + w*8 + l8 (covers 128 jointly over waves)
  const u16* bsrc[4]; int bch[4];
  #pragma unroll
  for (int j = 0; j < 4; j++){
    int rb = j * 32 + w * 8;
    bch[j] = rb * 128;
    bsrc[j] = BT + (bcol + rb + l8) * (size_t)FFD + csw;
  }
  // A ops q=0..3: rows wr*64 + q*16 + wc*8 + l8 (covers 128 jointly)
  const u16* asrc[4]; int ach[4];
  #pragma unroll
  for (int q = 0; q < 4; q++){
    int rb = wr * 64 + q * 16 + wc * 8;
    ach[q] = rb * 128;
    asrc[q] = Hb + (size_t)(browg + rb + l8) * FFD + csw;
  }

  f32x4 acc[4][4];
  #pragma unroll
  for (int m = 0; m < 4; m++)
    #pragma unroll
    for (int n = 0; n < 4; n++) acc[m][n] = (f32x4){0.f, 0.f, 0.f, 0.f};
  bf16x8 bC[8];

  const int NT = FFD / 64;  // 128

  // prologue: issue B(0)->Bs0, A(0)->As0, A(1)->As1 (12 loads);
  // need B(0)+A(0) done -> drain oldest 8 -> vmcnt(4)
  #pragma unroll
  for (int j = 0; j < 4; j++) gload_lds16(bsrc[j], (char*)Bs + bch[j]);
  #pragma unroll
  for (int q = 0; q < 4; q++) gload_lds16(asrc[q], (char*)As + ach[q]);
  #pragma unroll
  for (int q = 0; q < 4; q++) gload_lds16(asrc[q] + 64, (char*)As + 16384 + ach[q]);
  VMCNT(4); S_BARRIER();

  int sa = 0;   // A slot of current tile
  int sp = 2;   // A slot for tile t+2
  for (int t = 0; t < NT; ++t){
    const u16* asb = As + sa * 8192;
    const u16* bsb = Bs + (t & 1) * 8192;

    // reads: full B-frags + A m0,m1
    #pragma unroll
    for (int nf = 0; nf < 4; nf++){
      const u16* bp = bsb + (wc * 64 + nf * 16 + r16) * 64;
      bC[nf * 2]     = *(const bf16x8*)(bp + colk0);
      bC[nf * 2 + 1] = *(const bf16x8*)(bp + colk1);
    }
    bf16x8 a01[2][2];
    #pragma unroll
    for (int mi = 0; mi < 2; mi++){
      const u16* ap = asb + (wr * 64 + mi * 16 + r16) * 64;
      a01[mi][0] = *(const bf16x8*)(ap + colk0);
      a01[mi][1] = *(const bf16x8*)(ap + colk1);
    }

    // issue next-B (dbuf) then A(t+2) (tri-buffer)
    if (t + 1 < NT){
      char* bnb = (char*)Bs + ((t + 1) & 1) * 16384;
      const size_t ko = (size_t)(t + 1) * 64;
      #pragma unroll
      for (int j = 0; j < 4; j++) gload_lds16(bsrc[j] + ko, bnb + bch[j]);
    }
    if (t + 2 < NT){
      char* anb = (char*)As + sp * 16384;
      const size_t ko = (size_t)(t + 2) * 64;
      #pragma unroll
      for (int q = 0; q < 4; q++) gload_lds16(asrc[q] + ko, anb + ach[q]);
    }

    __builtin_amdgcn_s_setprio(1);
    #pragma unroll
    for (int mi = 0; mi < 2; mi++)
      #pragma unroll
      for (int nf = 0; nf < 4; nf++){
        acc[mi][nf] = mfma_bf16(a01[mi][0], bC[nf * 2],     acc[mi][nf]);
        acc[mi][nf] = mfma_bf16(a01[mi][1], bC[nf * 2 + 1], acc[mi][nf]);
      }
    __builtin_amdgcn_s_setprio(0);

    bf16x8 a23[2][2];
    #pragma unroll
    for (int mi = 0; mi < 2; mi++){
      const u16* ap = asb + (wr * 64 + (2 + mi) * 16 + r16) * 64;
      a23[mi][0] = *(const bf16x8*)(ap + colk0);
      a23[mi][1] = *(const bf16x8*)(ap + colk1);
    }
    __builtin_amdgcn_s_setprio(1);
    #pragma unroll
    for (int mi = 0; mi < 2; mi++)
      #pragma unroll
      for (int nf = 0; nf < 4; nf++){
        acc[2 + mi][nf] = mfma_bf16(a23[mi][0], bC[nf * 2],     acc[2 + mi][nf]);
        acc[2 + mi][nf] = mfma_bf16(a23[mi][1], bC[nf * 2 + 1], acc[2 + mi][nf]);
      }
    __builtin_amdgcn_s_setprio(0);

    // tile boundary: finish A(t+1)+B(t+1), keep A(t+2) in flight
    if      (t + 2 < NT) VMCNT(4);
    else if (t + 1 < NT) VMCNT(0);
    if (t + 1 < NT) S_BARRIER();

    sa = (sa == 2) ? 0 : sa + 1;
    sp = (sp == 2) ? 0 : sp + 1;
  }

  // epilogue: scatter-add (serialized expert dispatches + unique tokens -> race-free)
  const int cl = r16, rg = (lane >> 4) * 4;
  const size_t c0 = bcol + wc * 64;
  float bv[4];
  #pragma unroll
  for (int nf = 0; nf < 4; nf++) bv[nf] = bias[c0 + nf * 16 + cl];
  #pragma unroll
  for (int mf = 0; mf < 4; mf++){
    const int rbase = browg + wr * 64 + mf * 16 + rg;
    int   tok[4]; float gv[4];
    #pragma unroll
    for (int j = 0; j < 4; j++){
      const bool ok = (rbase + j) < Mv;
      tok[j] = ok ? rowidx[rbase + j] : -1;
      gv[j]  = ok ? gate[tok[j]] : 0.f;
    }
    #pragma unroll
    for (int nf = 0; nf < 4; nf++){
      const size_t col = c0 + nf * 16 + cl;
      #pragma unroll
      for (int j = 0; j < 4; j++){
        if (tok[j] >= 0){
          const size_t idx = (size_t)tok[j] * HD + col;
          Cout[idx] += gv[j] * (acc[mf][nf][j] + bv[nf]);
        }
      }
    }
  }
}

// ---------------- host ----------------
extern "C" void kernel_launch(void* const* d_in, const int* in_sizes, int n_in,
                              void* d_out, int out_size, void* d_ws, size_t ws_size,
                              hipStream_t stream){
  (void)in_sizes; (void)n_in; (void)ws_size;
  const float* X  = (const float*)d_in[0];
  const float* wg = (const float*)d_in[1];
  const float* bg = (const float*)d_in[2];
  const float* w1 = (const float*)d_in[3];
  const float* b1 = (const float*)d_in[4];
  const float* w2 = (const float*)d_in[5];
  const float* b2 = (const float*)d_in[6];
  float* out = (float*)d_out;

  char* ws = (char*)d_ws;
  size_t off = 0;
  auto alloc = [&](size_t b) -> char* {
    char* p = ws + off;
    off = (off + b + 255) & ~(size_t)255;
    return p;
  };
  u16*   Xb    = (u16*)  alloc((size_t)TOK * HD * 2);
  u16*   W1T   = (u16*)  alloc((size_t)FFD * HD * 2);
  u16*   W2T   = (u16*)  alloc((size_t)HD * FFD * 2);
  float* probs = (float*)alloc((size_t)TOK * 4 * 4);
  int*   topi  = (int*)  alloc((size_t)TOK * 2 * 4);
  float* gatew = (float*)alloc((size_t)NEXP * TOK * 4);
  int*   cnt   = (int*)  alloc((size_t)NEXP * 4);
  int*   lists = (int*)  alloc((size_t)NEXP * TOK * 4);
  u16*   Hb    = (u16*)  alloc((size_t)CAPE * FFD * 2);   // 68 MB

  hipMemsetAsync(cnt, 0, NEXP * sizeof(int), stream);
  hipMemsetAsync(out, 0, (size_t)TOK * HD * sizeof(float), stream);

  cvt_to_bf16<<<(TOK * HD / 4 + 255) / 256, 256, 0, stream>>>(X, Xb, TOK * HD / 4);
  router_kernel<<<TOK, 256, 0, stream>>>(X, wg, bg, probs, topi, gatew);
  build_lists<<<TOK / 256, 256, 0, stream>>>(topi, cnt, lists);
  aux_kernel<<<1, 256, 0, stream>>>(probs, topi, out + (out_size - 1));

  for (int e = 0; e < NEXP; ++e){
    transpose_cvt<<<dim3(FFD / 64, HD / 64), 256, 0, stream>>>(
        w1 + (size_t)e * HD * FFD, W1T, HD, FFD);
    transpose_cvt<<<dim3(HD / 64, FFD / 64), 256, 0, stream>>>(
        w2 + (size_t)e * FFD * HD, W2T, FFD, HD);
    gemm1_8p<<<dim3(FFD / 256, CAPE / 256), 512, 0, stream>>>(
        Xb, W1T, lists + e * TOK, cnt + e, b1 + (size_t)e * FFD, Hb);
    gemm2_tri<<<dim3(HD / 128, CAPE / 128), 256, 0, stream>>>(
        Hb, W2T, lists + e * TOK, cnt + e, b2 + (size_t)e * HD,
        gatew + (size_t)e * TOK, out);
  }
}

// Round 11
// 1837.248 us; speedup vs baseline: 1.4292x; 1.2011x over previous
//
#include <hip/hip_runtime.h>

typedef unsigned short u16;
typedef __attribute__((ext_vector_type(8))) short bf16x8;
typedef __attribute__((ext_vector_type(4))) float f32x4;

#define TOK  8192
#define HD   2048
#define FFD  8192
#define NEXP 4
#define CAPE 4352   // per-expert padded row capacity (E[Mv]=4096, sigma~45, +5.7σ)

#define S_BARRIER() asm volatile("s_barrier" ::: "memory")
#define VMCNT(n)    asm volatile("s_waitcnt vmcnt(" #n ")" ::: "memory")

__device__ __forceinline__ u16 f2bf(float f){
  unsigned u = __float_as_uint(f);
  u += 0x7fffu + ((u >> 16) & 1u);
  return (u16)(u >> 16);
}

__device__ __forceinline__ float gelu_tanh(float x){
  float u = 0.7978845608028654f * (x + 0.044715f * x * x * x);
  return 0.5f * x * (1.0f + tanhf(u));
}

__device__ __forceinline__ void gload_lds16(const void* g, void* l){
  __builtin_amdgcn_global_load_lds((const __attribute__((address_space(1))) void*)g,
                                   (__attribute__((address_space(3))) void*)l, 16, 0, 0);
}

__device__ __forceinline__ f32x4 mfma_bf16(bf16x8 a, bf16x8 b, f32x4 c){
  asm("v_mfma_f32_16x16x32_bf16 %0, %1, %2, %0" : "+v"(c) : "v"(a), "v"(b));
  return c;
}

// ---------------- conversions ----------------
__global__ __launch_bounds__(256) void cvt_to_bf16(const float* __restrict__ in,
                                                   u16* __restrict__ out, int n4){
  int i = blockIdx.x * 256 + threadIdx.x;
  if (i >= n4) return;
  float4 v = ((const float4*)in)[i];
  ushort4 o;
  o.x = f2bf(v.x); o.y = f2bf(v.y); o.z = f2bf(v.z); o.w = f2bf(v.w);
  ((ushort4*)out)[i] = o;
}

// in [R][C] f32  ->  out [C][R] bf16   (R3-proven version)
__global__ __launch_bounds__(256) void transpose_cvt(const float* __restrict__ in,
                                                     u16* __restrict__ out, int R, int C){
  __shared__ float tile[64][65];
  int tx = threadIdx.x & 63;
  int ty = threadIdx.x >> 6;
  size_t r0 = (size_t)blockIdx.y * 64;
  size_t c0 = (size_t)blockIdx.x * 64;
  #pragma unroll
  for (int i = ty; i < 64; i += 4)
    tile[i][tx] = in[(r0 + i) * C + (c0 + tx)];
  __syncthreads();
  #pragma unroll
  for (int i = ty; i < 64; i += 4)
    out[(c0 + i) * R + (r0 + tx)] = f2bf(tile[tx][i]);
}

// ---------------- router ----------------
__global__ __launch_bounds__(256) void router_kernel(
    const float* __restrict__ X, const float* __restrict__ wg, const float* __restrict__ bg,
    float* __restrict__ probs, int* __restrict__ topi, float* __restrict__ gatew){
  int t = blockIdx.x;
  const float* x = X + (size_t)t * HD;
  float a0 = 0.f, a1 = 0.f, a2 = 0.f, a3 = 0.f;
  for (int h = threadIdx.x; h < HD; h += 256){
    float xv = x[h];
    float4 w = ((const float4*)wg)[h];
    a0 += xv * w.x; a1 += xv * w.y; a2 += xv * w.z; a3 += xv * w.w;
  }
  __shared__ float red[4][256];
  red[0][threadIdx.x] = a0; red[1][threadIdx.x] = a1;
  red[2][threadIdx.x] = a2; red[3][threadIdx.x] = a3;
  __syncthreads();
  for (int s = 128; s > 0; s >>= 1){
    if (threadIdx.x < (unsigned)s){
      #pragma unroll
      for (int e = 0; e < 4; e++) red[e][threadIdx.x] += red[e][threadIdx.x + s];
    }
    __syncthreads();
  }
  if (threadIdx.x == 0){
    float l[4], p[4];
    #pragma unroll
    for (int e = 0; e < 4; e++) l[e] = red[e][0] + bg[e];
    float mx = fmaxf(fmaxf(l[0], l[1]), fmaxf(l[2], l[3]));
    float s = 0.f;
    #pragma unroll
    for (int e = 0; e < 4; e++){ p[e] = expf(l[e] - mx); s += p[e]; }
    #pragma unroll
    for (int e = 0; e < 4; e++){ p[e] /= s; probs[t * 4 + e] = p[e]; }
    int e0 = 0;
    for (int e = 1; e < 4; e++) if (p[e] > p[e0]) e0 = e;
    int e1 = -1;
    for (int e = 0; e < 4; e++){ if (e == e0) continue; if (e1 < 0 || p[e] > p[e1]) e1 = e; }
    float g = p[e0] + p[e1];
    topi[t * 2] = e0; topi[t * 2 + 1] = e1;
    #pragma unroll
    for (int e = 0; e < 4; e++)
      gatew[(size_t)e * TOK + t] = (e == e0) ? p[e0] / g : (e == e1) ? p[e1] / g : 0.f;
  }
}

// ---------------- expert token lists ----------------
__global__ __launch_bounds__(256) void build_lists(const int* __restrict__ topi,
                                                   int* __restrict__ cnt,
                                                   int* __restrict__ lists){
  int t = blockIdx.x * 256 + threadIdx.x;
  if (t >= TOK) return;
  #pragma unroll
  for (int k = 0; k < 2; k++){
    int e = topi[t * 2 + k];
    int p = atomicAdd(cnt + e, 1);
    lists[e * TOK + p] = t;
  }
}

// ---------------- aux loss ----------------
__global__ __launch_bounds__(256) void aux_kernel(const float* __restrict__ probs,
                                                  const int* __restrict__ topi,
                                                  float* __restrict__ out_aux){
  __shared__ float sp[4][256];
  __shared__ float sc[4][256];
  float p[4] = {0,0,0,0}, c[4] = {0,0,0,0};
  for (int t = threadIdx.x; t < TOK; t += 256){
    #pragma unroll
    for (int e = 0; e < 4; e++) p[e] += probs[t * 4 + e];
    c[topi[t * 2]]     += 1.f;
    c[topi[t * 2 + 1]] += 1.f;
  }
  #pragma unroll
  for (int e = 0; e < 4; e++){ sp[e][threadIdx.x] = p[e]; sc[e][threadIdx.x] = c[e]; }
  __syncthreads();
  for (int s = 128; s > 0; s >>= 1){
    if (threadIdx.x < (unsigned)s){
      #pragma unroll
      for (int e = 0; e < 4; e++){
        sp[e][threadIdx.x] += sp[e][threadIdx.x + s];
        sc[e][threadIdx.x] += sc[e][threadIdx.x + s];
      }
    }
    __syncthreads();
  }
  if (threadIdx.x == 0){
    float aux = 0.f;
    #pragma unroll
    for (int e = 0; e < 4; e++)
      aux += (sc[e][0] / (float)(TOK * 2)) * (sp[e][0] / (float)TOK);
    *out_aux = 4.f * aux;
  }
}

// =====================================================================
// GEMM1: 256x256 tile, BK=64, 512 thr (8 waves 2x4, wave-tile 128x64),
// 8-phase (4/tile) counted-vmcnt pipeline, st-swizzled LDS, A gathered.
// =====================================================================
__global__ __launch_bounds__(512, 2) void gemm1_8p(
    const u16* __restrict__ Xb, const u16* __restrict__ BT,
    const int* __restrict__ rowidx, const int* __restrict__ cntp,
    const float* __restrict__ bias, u16* __restrict__ Hout)
{
  __shared__ __align__(16) u16 As[2 * 256 * 64];   // 64 KB
  __shared__ __align__(16) u16 Bs[2 * 256 * 64];   // 64 KB
  const int Mv = *cntp;
  const int nwg = gridDim.x * gridDim.y;
  const int orig = blockIdx.x + gridDim.x * blockIdx.y;
  const int q8 = nwg >> 3, r8 = nwg & 7, xcd = orig & 7, rank = orig >> 3;
  const int v = (xcd < r8 ? xcd * (q8 + 1) : r8 * (q8 + 1) + (xcd - r8) * q8) + rank;
  const int by = v % (int)gridDim.y, bx = v / (int)gridDim.y;
  const int browg = by * 256;
  if (browg >= Mv) return;
  const size_t bcol = (size_t)bx * 256;

  const int tid = threadIdx.x, lane = tid & 63, w = tid >> 6;
  const int wr = w >> 2, wc = w & 3;
  const int l8 = lane >> 3;
  const int csw  = ((lane & 7) ^ l8) * 8;          // stage-src col swizzle (elems)
  const int sw   = (lane & 7) * 8;
  const int h8   = ((lane >> 4) & 3) * 8;
  const int colk0 = h8 ^ sw, colk1 = (32 | h8) ^ sw; // ds_read col swizzle
  const int r16 = lane & 15;

  const u16* bsrc[4]; int bch[4];
  #pragma unroll
  for (int j = 0; j < 4; j++){
    int rb = wc * 64 + wr * 32 + j * 8;
    bch[j] = rb * 128;
    bsrc[j] = BT + (bcol + rb + l8) * (size_t)HD + csw;
  }
  const u16* asrc[4]; int ach[4];
  #pragma unroll
  for (int q = 0; q < 4; q++){
    int rb = wr * 128 + q * 32 + wc * 8;
    ach[q] = rb * 128;
    int rl = browg + rb + l8; if (rl > Mv - 1) rl = Mv - 1;
    asrc[q] = Xb + (size_t)rowidx[rl] * HD + csw;
  }

  f32x4 acc[8][4];
  #pragma unroll
  for (int m = 0; m < 8; m++)
    #pragma unroll
    for (int n = 0; n < 4; n++) acc[m][n] = (f32x4){0.f, 0.f, 0.f, 0.f};
  bf16x8 bC[8];

  const int NT = HD / 64;  // 32
  #pragma unroll
  for (int j = 0; j < 4; j++) gload_lds16(bsrc[j], (char*)Bs + bch[j]);
  #pragma unroll
  for (int q = 0; q < 4; q++) gload_lds16(asrc[q], (char*)As + ach[q]);
  VMCNT(3); S_BARRIER();

  for (int t = 0; t < NT; ++t){
    const u16* asb = As + (t & 1) * 16384;
    const u16* bsb = Bs + (t & 1) * 16384;
    char* anb = (char*)As + ((t & 1) ^ 1) * 32768;
    char* bnb = (char*)Bs + ((t & 1) ^ 1) * 32768;
    const size_t ko = (size_t)(t + 1) * 64;
    const bool lastT = (t == NT - 1);
    #pragma unroll 4
    for (int p = 0; p < 4; p++){
      if (p == 0){
        #pragma unroll
        for (int nf = 0; nf < 4; nf++){
          const u16* bp = bsb + (wc * 64 + nf * 16 + r16) * 64;
          bC[nf * 2]     = *(const bf16x8*)(bp + colk0);
          bC[nf * 2 + 1] = *(const bf16x8*)(bp + colk1);
        }
      }
      bf16x8 a[2][2];
      #pragma unroll
      for (int mi = 0; mi < 2; mi++){
        const u16* ap = asb + (wr * 128 + (2 * p + mi) * 16 + r16) * 64;
        a[mi][0] = *(const bf16x8*)(ap + colk0);
        a[mi][1] = *(const bf16x8*)(ap + colk1);
      }
      if (!lastT){
        if      (p == 0){ gload_lds16(bsrc[0] + ko, bnb + bch[0]); gload_lds16(bsrc[1] + ko, bnb + bch[1]); }
        else if (p == 1){ gload_lds16(bsrc[2] + ko, bnb + bch[2]); gload_lds16(bsrc[3] + ko, bnb + bch[3]); }
        else if (p == 2){ gload_lds16(asrc[0] + ko, anb + ach[0]); gload_lds16(asrc[1] + ko, anb + ach[1]); }
        else            { gload_lds16(asrc[2] + ko, anb + ach[2]); gload_lds16(asrc[3] + ko, anb + ach[3]); }
      }
      S_BARRIER();
      __builtin_amdgcn_s_setprio(1);
      #pragma unroll
      for (int mi = 0; mi < 2; mi++)
        #pragma unroll
        for (int nf = 0; nf < 4; nf++){
          acc[2 * p + mi][nf] = mfma_bf16(a[mi][0], bC[nf * 2],     acc[2 * p + mi][nf]);
          acc[2 * p + mi][nf] = mfma_bf16(a[mi][1], bC[nf * 2 + 1], acc[2 * p + mi][nf]);
        }
      __builtin_amdgcn_s_setprio(0);
      if (!lastT){ if (p == 0) VMCNT(4); else if (p == 1) VMCNT(5); else if (p == 2) VMCNT(6); else VMCNT(3); }
      else       { if (p == 0) VMCNT(2); else if (p == 1) VMCNT(1); else if (p == 2) VMCNT(0); }
      S_BARRIER();
    }
  }

  const int cl = r16, rg = (lane >> 4) * 4;
  const size_t c0 = bcol + wc * 64;
  float bv[4];
  #pragma unroll
  for (int nf = 0; nf < 4; nf++) bv[nf] = bias[c0 + nf * 16 + cl];
  #pragma unroll
  for (int mf = 0; mf < 8; mf++){
    const size_t rb = (size_t)(browg + wr * 128 + mf * 16 + rg);
    #pragma unroll
    for (int nf = 0; nf < 4; nf++){
      const size_t col = c0 + nf * 16 + cl;
      #pragma unroll
      for (int j = 0; j < 4; j++)
        Hout[(rb + j) * FFD + col] = f2bf(gelu_tanh(acc[mf][nf][j] + bv[nf]));
    }
  }
}

// =====================================================================
// GEMM2: 128x128 tile, BK=64, 256 thr (4 waves 2x2, wave-tile 64x64).
// R10->R11: m97-style SINGLE-buffered 32 KB LDS -> 5 blocks/CU.
// Latency hiding via cross-block TLP (m97/m103: 36% MfmaUtil at 128²),
// not intra-block pipelining (R7/R8/R9 all ~20%). Swizzled stage+read
// (0 conflicts), y-major XCD order. 2 barriers/tile, vmcnt(0) drain
// handled by __syncthreads(). out[tok] += gate[tok]*(H @ W2T^T + b2)
// =====================================================================
__global__ __launch_bounds__(256) void gemm2_97(
    const u16* __restrict__ Hb, const u16* __restrict__ BT,
    const int* __restrict__ rowidx, const int* __restrict__ cntp,
    const float* __restrict__ bias, const float* __restrict__ gate,
    float* __restrict__ Cout)
{
  __shared__ __align__(16) u16 As[128 * 64];   // 16 KB
  __shared__ __align__(16) u16 Bs[128 * 64];   // 16 KB  (32 KB total -> 5 blocks/CU)
  const int Mv = *cntp;
  const int nwg = gridDim.x * gridDim.y;
  const int orig = blockIdx.x + gridDim.x * blockIdx.y;
  const int q8 = nwg >> 3, r8 = nwg & 7, xcd = orig & 7, rank = orig >> 3;
  const int v = (xcd < r8 ? xcd * (q8 + 1) : r8 * (q8 + 1) + (xcd - r8) * q8) + rank;
  const int bx = v % (int)gridDim.x, by = v / (int)gridDim.x;   // y-major: A-band hot
  const int browg = by * 128;
  if (browg >= Mv) return;
  const size_t bcol = (size_t)bx * 128;

  const int tid = threadIdx.x, lane = tid & 63, w = tid >> 6;   // 4 waves 2x2
  const int wr = w >> 1, wc = w & 1;
  const int l8 = lane >> 3;
  const int csw  = ((lane & 7) ^ l8) * 8;
  const int sw   = (lane & 7) * 8;
  const int h8   = ((lane >> 4) & 3) * 8;
  const int colk0 = h8 ^ sw, colk1 = (32 | h8) ^ sw;
  const int r16 = lane & 15;

  // B ops j=0..3: rows j*32 + w*8 + l8 (covers 128 jointly over waves)
  const u16* bsrc[4]; int bch[4];
  #pragma unroll
  for (int j = 0; j < 4; j++){
    int rb = j * 32 + w * 8;
    bch[j] = rb * 128;
    bsrc[j] = BT + (bcol + rb + l8) * (size_t)FFD + csw;
  }
  // A ops q=0..3: rows wr*64 + q*16 + wc*8 + l8 (covers 128 jointly)
  const u16* asrc[4]; int ach[4];
  #pragma unroll
  for (int q = 0; q < 4; q++){
    int rb = wr * 64 + q * 16 + wc * 8;
    ach[q] = rb * 128;
    asrc[q] = Hb + (size_t)(browg + rb + l8) * FFD + csw;
  }

  f32x4 acc[4][4];
  #pragma unroll
  for (int m = 0; m < 4; m++)
    #pragma unroll
    for (int n = 0; n < 4; n++) acc[m][n] = (f32x4){0.f, 0.f, 0.f, 0.f};
  bf16x8 bC[8];

  const int NT = FFD / 64;  // 128
  for (int t = 0; t < NT; ++t){
    const size_t ko = (size_t)t * 64;
    __syncthreads();                        // prev tile's ds_reads done before overwrite
    #pragma unroll
    for (int j = 0; j < 4; j++) gload_lds16(bsrc[j] + ko, (char*)Bs + bch[j]);
    #pragma unroll
    for (int q = 0; q < 4; q++) gload_lds16(asrc[q] + ko, (char*)As + ach[q]);
    __syncthreads();                        // drains vmcnt(0) before barrier

    #pragma unroll
    for (int nf = 0; nf < 4; nf++){
      const u16* bp = Bs + (wc * 64 + nf * 16 + r16) * 64;
      bC[nf * 2]     = *(const bf16x8*)(bp + colk0);
      bC[nf * 2 + 1] = *(const bf16x8*)(bp + colk1);
    }
    #pragma unroll
    for (int m = 0; m < 4; m++){
      const u16* ap = As + (wr * 64 + m * 16 + r16) * 64;
      bf16x8 a0 = *(const bf16x8*)(ap + colk0);
      bf16x8 a1 = *(const bf16x8*)(ap + colk1);
      #pragma unroll
      for (int nf = 0; nf < 4; nf++){
        acc[m][nf] = mfma_bf16(a0, bC[nf * 2],     acc[m][nf]);
        acc[m][nf] = mfma_bf16(a1, bC[nf * 2 + 1], acc[m][nf]);
      }
    }
  }

  // epilogue: scatter-add (serialized expert dispatches + unique tokens -> race-free)
  const int cl = r16, rg = (lane >> 4) * 4;
  const size_t c0 = bcol + wc * 64;
  float bv[4];
  #pragma unroll
  for (int nf = 0; nf < 4; nf++) bv[nf] = bias[c0 + nf * 16 + cl];
  #pragma unroll
  for (int mf = 0; mf < 4; mf++){
    const int rbase = browg + wr * 64 + mf * 16 + rg;
    int   tok[4]; float gv[4];
    #pragma unroll
    for (int j = 0; j < 4; j++){
      const bool ok = (rbase + j) < Mv;
      tok[j] = ok ? rowidx[rbase + j] : -1;
      gv[j]  = ok ? gate[tok[j]] : 0.f;
    }
    #pragma unroll
    for (int nf = 0; nf < 4; nf++){
      const size_t col = c0 + nf * 16 + cl;
      #pragma unroll
      for (int j = 0; j < 4; j++){
        if (tok[j] >= 0){
          const size_t idx = (size_t)tok[j] * HD + col;
          Cout[idx] += gv[j] * (acc[mf][nf][j] + bv[nf]);
        }
      }
    }
  }
}

// ---------------- host ----------------
extern "C" void kernel_launch(void* const* d_in, const int* in_sizes, int n_in,
                              void* d_out, int out_size, void* d_ws, size_t ws_size,
                              hipStream_t stream){
  (void)in_sizes; (void)n_in; (void)ws_size;
  const float* X  = (const float*)d_in[0];
  const float* wg = (const float*)d_in[1];
  const float* bg = (const float*)d_in[2];
  const float* w1 = (const float*)d_in[3];
  const float* b1 = (const float*)d_in[4];
  const float* w2 = (const float*)d_in[5];
  const float* b2 = (const float*)d_in[6];
  float* out = (float*)d_out;

  char* ws = (char*)d_ws;
  size_t off = 0;
  auto alloc = [&](size_t b) -> char* {
    char* p = ws + off;
    off = (off + b + 255) & ~(size_t)255;
    return p;
  };
  u16*   Xb    = (u16*)  alloc((size_t)TOK * HD * 2);
  u16*   W1T   = (u16*)  alloc((size_t)FFD * HD * 2);
  u16*   W2T   = (u16*)  alloc((size_t)HD * FFD * 2);
  float* probs = (float*)alloc((size_t)TOK * 4 * 4);
  int*   topi  = (int*)  alloc((size_t)TOK * 2 * 4);
  float* gatew = (float*)alloc((size_t)NEXP * TOK * 4);
  int*   cnt   = (int*)  alloc((size_t)NEXP * 4);
  int*   lists = (int*)  alloc((size_t)NEXP * TOK * 4);
  u16*   Hb    = (u16*)  alloc((size_t)CAPE * FFD * 2);   // 68 MB

  hipMemsetAsync(cnt, 0, NEXP * sizeof(int), stream);
  hipMemsetAsync(out, 0, (size_t)TOK * HD * sizeof(float), stream);

  cvt_to_bf16<<<(TOK * HD / 4 + 255) / 256, 256, 0, stream>>>(X, Xb, TOK * HD / 4);
  router_kernel<<<TOK, 256, 0, stream>>>(X, wg, bg, probs, topi, gatew);
  build_lists<<<TOK / 256, 256, 0, stream>>>(topi, cnt, lists);
  aux_kernel<<<1, 256, 0, stream>>>(probs, topi, out + (out_size - 1));

  for (int e = 0; e < NEXP; ++e){
    transpose_cvt<<<dim3(FFD / 64, HD / 64), 256, 0, stream>>>(
        w1 + (size_t)e * HD * FFD, W1T, HD, FFD);
    transpose_cvt<<<dim3(HD / 64, FFD / 64), 256, 0, stream>>>(
        w2 + (size_t)e * FFD * HD, W2T, FFD, HD);
    gemm1_8p<<<dim3(FFD / 256, CAPE / 256), 512, 0, stream>>>(
        Xb, W1T, lists + e * TOK, cnt + e, b1 + (size_t)e * FFD, Hb);
    gemm2_97<<<dim3(HD / 128, CAPE / 128), 256, 0, stream>>>(
        Hb, W2T, lists + e * TOK, cnt + e, b2 + (size_t)e * HD,
        gatew + (size_t)e * TOK, out);
  }
}

// Round 12
// 1830.496 us; speedup vs baseline: 1.4344x; 1.0037x over previous
//
#include <hip/hip_runtime.h>

typedef unsigned short u16;
typedef __attribute__((ext_vector_type(8))) short bf16x8;
typedef __attribute__((ext_vector_type(4))) float f32x4;

#define TOK  8192
#define HD   2048
#define FFD  8192
#define NEXP 4
#define CAPE 4352   // per-expert padded row capacity (E[Mv]=4096, sigma~45, +5.7σ)

__device__ __forceinline__ u16 f2bf(float f){
  unsigned u = __float_as_uint(f);
  u += 0x7fffu + ((u >> 16) & 1u);
  return (u16)(u >> 16);
}

__device__ __forceinline__ float gelu_tanh(float x){
  float u = 0.7978845608028654f * (x + 0.044715f * x * x * x);
  return 0.5f * x * (1.0f + tanhf(u));
}

__device__ __forceinline__ void gload_lds16(const void* g, void* l){
  __builtin_amdgcn_global_load_lds((const __attribute__((address_space(1))) void*)g,
                                   (__attribute__((address_space(3))) void*)l, 16, 0, 0);
}

__device__ __forceinline__ f32x4 mfma_bf16(bf16x8 a, bf16x8 b, f32x4 c){
  asm("v_mfma_f32_16x16x32_bf16 %0, %1, %2, %0" : "+v"(c) : "v"(a), "v"(b));
  return c;
}

// ---------------- conversions ----------------
__global__ __launch_bounds__(256) void cvt_to_bf16(const float* __restrict__ in,
                                                   u16* __restrict__ out, int n4){
  int i = blockIdx.x * 256 + threadIdx.x;
  if (i >= n4) return;
  float4 v = ((const float4*)in)[i];
  ushort4 o;
  o.x = f2bf(v.x); o.y = f2bf(v.y); o.z = f2bf(v.z); o.w = f2bf(v.w);
  ((ushort4*)out)[i] = o;
}

// in [R][C] f32  ->  out [C][R] bf16   (R3-proven version)
__global__ __launch_bounds__(256) void transpose_cvt(const float* __restrict__ in,
                                                     u16* __restrict__ out, int R, int C){
  __shared__ float tile[64][65];
  int tx = threadIdx.x & 63;
  int ty = threadIdx.x >> 6;
  size_t r0 = (size_t)blockIdx.y * 64;
  size_t c0 = (size_t)blockIdx.x * 64;
  #pragma unroll
  for (int i = ty; i < 64; i += 4)
    tile[i][tx] = in[(r0 + i) * C + (c0 + tx)];
  __syncthreads();
  #pragma unroll
  for (int i = ty; i < 64; i += 4)
    out[(c0 + i) * R + (r0 + tx)] = f2bf(tile[tx][i]);
}

// ---------------- router ----------------
__global__ __launch_bounds__(256) void router_kernel(
    const float* __restrict__ X, const float* __restrict__ wg, const float* __restrict__ bg,
    float* __restrict__ probs, int* __restrict__ topi, float* __restrict__ gatew){
  int t = blockIdx.x;
  const float* x = X + (size_t)t * HD;
  float a0 = 0.f, a1 = 0.f, a2 = 0.f, a3 = 0.f;
  for (int h = threadIdx.x; h < HD; h += 256){
    float xv = x[h];
    float4 w = ((const float4*)wg)[h];
    a0 += xv * w.x; a1 += xv * w.y; a2 += xv * w.z; a3 += xv * w.w;
  }
  __shared__ float red[4][256];
  red[0][threadIdx.x] = a0; red[1][threadIdx.x] = a1;
  red[2][threadIdx.x] = a2; red[3][threadIdx.x] = a3;
  __syncthreads();
  for (int s = 128; s > 0; s >>= 1){
    if (threadIdx.x < (unsigned)s){
      #pragma unroll
      for (int e = 0; e < 4; e++) red[e][threadIdx.x] += red[e][threadIdx.x + s];
    }
    __syncthreads();
  }
  if (threadIdx.x == 0){
    float l[4], p[4];
    #pragma unroll
    for (int e = 0; e < 4; e++) l[e] = red[e][0] + bg[e];
    float mx = fmaxf(fmaxf(l[0], l[1]), fmaxf(l[2], l[3]));
    float s = 0.f;
    #pragma unroll
    for (int e = 0; e < 4; e++){ p[e] = expf(l[e] - mx); s += p[e]; }
    #pragma unroll
    for (int e = 0; e < 4; e++){ p[e] /= s; probs[t * 4 + e] = p[e]; }
    int e0 = 0;
    for (int e = 1; e < 4; e++) if (p[e] > p[e0]) e0 = e;
    int e1 = -1;
    for (int e = 0; e < 4; e++){ if (e == e0) continue; if (e1 < 0 || p[e] > p[e1]) e1 = e; }
    float g = p[e0] + p[e1];
    topi[t * 2] = e0; topi[t * 2 + 1] = e1;
    #pragma unroll
    for (int e = 0; e < 4; e++)
      gatew[(size_t)e * TOK + t] = (e == e0) ? p[e0] / g : (e == e1) ? p[e1] / g : 0.f;
  }
}

// ---------------- expert token lists ----------------
__global__ __launch_bounds__(256) void build_lists(const int* __restrict__ topi,
                                                   int* __restrict__ cnt,
                                                   int* __restrict__ lists){
  int t = blockIdx.x * 256 + threadIdx.x;
  if (t >= TOK) return;
  #pragma unroll
  for (int k = 0; k < 2; k++){
    int e = topi[t * 2 + k];
    int p = atomicAdd(cnt + e, 1);
    lists[e * TOK + p] = t;
  }
}

// ---------------- aux loss ----------------
__global__ __launch_bounds__(256) void aux_kernel(const float* __restrict__ probs,
                                                  const int* __restrict__ topi,
                                                  float* __restrict__ out_aux){
  __shared__ float sp[4][256];
  __shared__ float sc[4][256];
  float p[4] = {0,0,0,0}, c[4] = {0,0,0,0};
  for (int t = threadIdx.x; t < TOK; t += 256){
    #pragma unroll
    for (int e = 0; e < 4; e++) p[e] += probs[t * 4 + e];
    c[topi[t * 2]]     += 1.f;
    c[topi[t * 2 + 1]] += 1.f;
  }
  #pragma unroll
  for (int e = 0; e < 4; e++){ sp[e][threadIdx.x] = p[e]; sc[e][threadIdx.x] = c[e]; }
  __syncthreads();
  for (int s = 128; s > 0; s >>= 1){
    if (threadIdx.x < (unsigned)s){
      #pragma unroll
      for (int e = 0; e < 4; e++){
        sp[e][threadIdx.x] += sp[e][threadIdx.x + s];
        sc[e][threadIdx.x] += sc[e][threadIdx.x + s];
      }
    }
    __syncthreads();
  }
  if (threadIdx.x == 0){
    float aux = 0.f;
    #pragma unroll
    for (int e = 0; e < 4; e++)
      aux += (sc[e][0] / (float)(TOK * 2)) * (sp[e][0] / (float)TOK);
    *out_aux = 4.f * aux;
  }
}

// =====================================================================
// Unified m97-style MoE GEMM (R11's winning gemm2_97 structure).
// 128x128 tile, BK=64, 256 thr (4 waves 2x2, wave-tile 64x64),
// SINGLE-buffered 32 KB LDS -> 5 blocks/CU (TLP hides latency — beat
// all pipelined variants R7/R8/R9 by ~2x). Swizzled stage+read (0
// conflicts), bijective XCD order, consecutive ranks share A-band.
// EPI 0: A = Xb gathered via rowidx (clamped); Hb[row] = gelu(acc+b1)
// EPI 1: A = Hb; out[tok] += gate[tok]*(acc+b2)  (masked scatter-add)
// =====================================================================
template<int EPI, int N, int K>
__global__ __launch_bounds__(256) void gemm_97(
    const u16* __restrict__ A, const u16* __restrict__ BT,
    const int* __restrict__ rowidx, const int* __restrict__ cntp,
    const float* __restrict__ bias,
    u16* __restrict__ Hout,
    const float* __restrict__ gate, float* __restrict__ Cout)
{
  __shared__ __align__(16) u16 As[128 * 64];   // 16 KB
  __shared__ __align__(16) u16 Bs[128 * 64];   // 16 KB  (32 KB total)
  const int Mv = *cntp;
  const int nwg = gridDim.x * gridDim.y;
  const int orig = blockIdx.x + gridDim.x * blockIdx.y;
  const int q8 = nwg >> 3, r8 = nwg & 7, xcd = orig & 7, rank = orig >> 3;
  const int v = (xcd < r8 ? xcd * (q8 + 1) : r8 * (q8 + 1) + (xcd - r8) * q8) + rank;
  const int bx = v % (int)gridDim.x, by = v / (int)gridDim.x;   // consecutive: A-band hot
  const int browg = by * 128;
  if (browg >= Mv) return;
  const size_t bcol = (size_t)bx * 128;

  const int tid = threadIdx.x, lane = tid & 63, w = tid >> 6;   // 4 waves 2x2
  const int wr = w >> 1, wc = w & 1;
  const int l8 = lane >> 3;
  const int csw  = ((lane & 7) ^ l8) * 8;
  const int sw   = (lane & 7) * 8;
  const int h8   = ((lane >> 4) & 3) * 8;
  const int colk0 = h8 ^ sw, colk1 = (32 | h8) ^ sw;
  const int r16 = lane & 15;

  // B ops j=0..3: rows j*32 + w*8 + l8 (covers 128 jointly over waves)
  const u16* bsrc[4]; int bch[4];
  #pragma unroll
  for (int j = 0; j < 4; j++){
    int rb = j * 32 + w * 8;
    bch[j] = rb * 128;
    bsrc[j] = BT + (bcol + rb + l8) * (size_t)K + csw;
  }
  // A ops q=0..3: rows wr*64 + q*16 + wc*8 + l8 (covers 128 jointly)
  const u16* asrc[4]; int ach[4];
  #pragma unroll
  for (int q = 0; q < 4; q++){
    int rb = wr * 64 + q * 16 + wc * 8;
    ach[q] = rb * 128;
    int rl = browg + rb + l8;
    int ar;
    if (EPI == 0){
      if (rl > Mv - 1) rl = Mv - 1;   // clamp pad rows to a valid token
      ar = rowidx[rl];
    } else {
      ar = rl;                        // Hb expert-local row (pad rows finite garbage, masked at EPI)
    }
    asrc[q] = A + (size_t)ar * K + csw;
  }

  f32x4 acc[4][4];
  #pragma unroll
  for (int m = 0; m < 4; m++)
    #pragma unroll
    for (int n = 0; n < 4; n++) acc[m][n] = (f32x4){0.f, 0.f, 0.f, 0.f};
  bf16x8 bC[8];

  const int NT = K / 64;
  for (int t = 0; t < NT; ++t){
    const size_t ko = (size_t)t * 64;
    __syncthreads();                        // prev tile's ds_reads done before overwrite
    #pragma unroll
    for (int j = 0; j < 4; j++) gload_lds16(bsrc[j] + ko, (char*)Bs + bch[j]);
    #pragma unroll
    for (int q = 0; q < 4; q++) gload_lds16(asrc[q] + ko, (char*)As + ach[q]);
    __syncthreads();                        // drains vmcnt(0) before barrier

    #pragma unroll
    for (int nf = 0; nf < 4; nf++){
      const u16* bp = Bs + (wc * 64 + nf * 16 + r16) * 64;
      bC[nf * 2]     = *(const bf16x8*)(bp + colk0);
      bC[nf * 2 + 1] = *(const bf16x8*)(bp + colk1);
    }
    #pragma unroll
    for (int m = 0; m < 4; m++){
      const u16* ap = As + (wr * 64 + m * 16 + r16) * 64;
      bf16x8 a0 = *(const bf16x8*)(ap + colk0);
      bf16x8 a1 = *(const bf16x8*)(ap + colk1);
      #pragma unroll
      for (int nf = 0; nf < 4; nf++){
        acc[m][nf] = mfma_bf16(a0, bC[nf * 2],     acc[m][nf]);
        acc[m][nf] = mfma_bf16(a1, bC[nf * 2 + 1], acc[m][nf]);
      }
    }
  }

  // epilogue
  const int cl = r16, rg = (lane >> 4) * 4;
  const size_t c0 = bcol + wc * 64;
  float bv[4];
  #pragma unroll
  for (int nf = 0; nf < 4; nf++) bv[nf] = bias[c0 + nf * 16 + cl];
  #pragma unroll
  for (int mf = 0; mf < 4; mf++){
    const int rbase = browg + wr * 64 + mf * 16 + rg;
    if (EPI == 0){
      #pragma unroll
      for (int nf = 0; nf < 4; nf++){
        const size_t col = c0 + nf * 16 + cl;
        #pragma unroll
        for (int j = 0; j < 4; j++)
          Hout[(size_t)(rbase + j) * N + col] = f2bf(gelu_tanh(acc[mf][nf][j] + bv[nf]));
      }
    } else {
      int   tok[4]; float gv[4];
      #pragma unroll
      for (int j = 0; j < 4; j++){
        const bool ok = (rbase + j) < Mv;
        tok[j] = ok ? rowidx[rbase + j] : -1;
        gv[j]  = ok ? gate[tok[j]] : 0.f;
      }
      #pragma unroll
      for (int nf = 0; nf < 4; nf++){
        const size_t col = c0 + nf * 16 + cl;
        #pragma unroll
        for (int j = 0; j < 4; j++){
          if (tok[j] >= 0){
            const size_t idx = (size_t)tok[j] * N + col;
            Cout[idx] += gv[j] * (acc[mf][nf][j] + bv[nf]);  // serialized dispatches -> race-free
          }
        }
      }
    }
  }
}

// ---------------- host ----------------
extern "C" void kernel_launch(void* const* d_in, const int* in_sizes, int n_in,
                              void* d_out, int out_size, void* d_ws, size_t ws_size,
                              hipStream_t stream){
  (void)in_sizes; (void)n_in; (void)ws_size;
  const float* X  = (const float*)d_in[0];
  const float* wg = (const float*)d_in[1];
  const float* bg = (const float*)d_in[2];
  const float* w1 = (const float*)d_in[3];
  const float* b1 = (const float*)d_in[4];
  const float* w2 = (const float*)d_in[5];
  const float* b2 = (const float*)d_in[6];
  float* out = (float*)d_out;

  char* ws = (char*)d_ws;
  size_t off = 0;
  auto alloc = [&](size_t b) -> char* {
    char* p = ws + off;
    off = (off + b + 255) & ~(size_t)255;
    return p;
  };
  u16*   Xb    = (u16*)  alloc((size_t)TOK * HD * 2);
  u16*   W1T   = (u16*)  alloc((size_t)FFD * HD * 2);
  u16*   W2T   = (u16*)  alloc((size_t)HD * FFD * 2);
  float* probs = (float*)alloc((size_t)TOK * 4 * 4);
  int*   topi  = (int*)  alloc((size_t)TOK * 2 * 4);
  float* gatew = (float*)alloc((size_t)NEXP * TOK * 4);
  int*   cnt   = (int*)  alloc((size_t)NEXP * 4);
  int*   lists = (int*)  alloc((size_t)NEXP * TOK * 4);
  u16*   Hb    = (u16*)  alloc((size_t)CAPE * FFD * 2);   // 68 MB

  hipMemsetAsync(cnt, 0, NEXP * sizeof(int), stream);
  hipMemsetAsync(out, 0, (size_t)TOK * HD * sizeof(float), stream);

  cvt_to_bf16<<<(TOK * HD / 4 + 255) / 256, 256, 0, stream>>>(X, Xb, TOK * HD / 4);
  router_kernel<<<TOK, 256, 0, stream>>>(X, wg, bg, probs, topi, gatew);
  build_lists<<<TOK / 256, 256, 0, stream>>>(topi, cnt, lists);
  aux_kernel<<<1, 256, 0, stream>>>(probs, topi, out + (out_size - 1));

  for (int e = 0; e < NEXP; ++e){
    transpose_cvt<<<dim3(FFD / 64, HD / 64), 256, 0, stream>>>(
        w1 + (size_t)e * HD * FFD, W1T, HD, FFD);
    transpose_cvt<<<dim3(HD / 64, FFD / 64), 256, 0, stream>>>(
        w2 + (size_t)e * FFD * HD, W2T, FFD, HD);
    gemm_97<0, FFD, HD><<<dim3(FFD / 128, CAPE / 128), 256, 0, stream>>>(
        Xb, W1T, lists + e * TOK, cnt + e, b1 + (size_t)e * FFD,
        Hb, nullptr, nullptr);
    gemm_97<1, HD, FFD><<<dim3(HD / 128, CAPE / 128), 256, 0, stream>>>(
        Hb, W2T, lists + e * TOK, cnt + e, b2 + (size_t)e * HD,
        nullptr, gatew + (size_t)e * TOK, out);
  }
}

// Round 13
// 1694.364 us; speedup vs baseline: 1.5497x; 1.0803x over previous
//
#include <hip/hip_runtime.h>

typedef unsigned short u16;
typedef __attribute__((ext_vector_type(8))) short bf16x8;
typedef __attribute__((ext_vector_type(4))) float f32x4;

#define TOK  8192
#define HD   2048
#define FFD  8192
#define NEXP 4
#define CAPE 4352   // per-expert padded row capacity (E[Mv]=4096, sigma~45, +5.7σ)

__device__ __forceinline__ u16 f2bf(float f){
  unsigned u = __float_as_uint(f);
  u += 0x7fffu + ((u >> 16) & 1u);
  return (u16)(u >> 16);
}

__device__ __forceinline__ float gelu_tanh(float x){
  float u = 0.7978845608028654f * (x + 0.044715f * x * x * x);
  return 0.5f * x * (1.0f + tanhf(u));
}

__device__ __forceinline__ void gload_lds16(const void* g, void* l){
  __builtin_amdgcn_global_load_lds((const __attribute__((address_space(1))) void*)g,
                                   (__attribute__((address_space(3))) void*)l, 16, 0, 0);
}

__device__ __forceinline__ f32x4 mfma_bf16(bf16x8 a, bf16x8 b, f32x4 c){
  asm("v_mfma_f32_16x16x32_bf16 %0, %1, %2, %0" : "+v"(c) : "v"(a), "v"(b));
  return c;
}

// ---------------- conversions ----------------
__global__ __launch_bounds__(256) void cvt_to_bf16(const float* __restrict__ in,
                                                   u16* __restrict__ out, int n4){
  int i = blockIdx.x * 256 + threadIdx.x;
  if (i >= n4) return;
  float4 v = ((const float4*)in)[i];
  ushort4 o;
  o.x = f2bf(v.x); o.y = f2bf(v.y); o.z = f2bf(v.z); o.w = f2bf(v.w);
  ((ushort4*)out)[i] = o;
}

// in [R][C] f32 -> out [C][R] bf16. 128(r) x 64(c) tiles, bf16 LDS,
// ushort2 stores: 256B/wave-instr both phases; LDS 2-way-free both phases.
__global__ __launch_bounds__(256) void transpose_cvt(const float* __restrict__ in,
                                                     u16* __restrict__ out, int R, int C){
  __shared__ u16 t[64][138];               // 17.7 KB; stride 276B -> banks (69c+tx)%32
  const int tx = threadIdx.x & 63;
  const int w  = threadIdx.x >> 6;
  const size_t r0 = (size_t)blockIdx.y * 128;
  const size_t c0 = (size_t)blockIdx.x * 64;
  #pragma unroll
  for (int i = 0; i < 32; i++){
    const int r = w * 32 + i;
    t[tx][r] = f2bf(in[(r0 + r) * C + c0 + tx]);   // 256B coalesced read
  }
  __syncthreads();
  #pragma unroll
  for (int j = 0; j < 16; j++){
    const int c = j * 4 + w;
    ushort2 o;
    o.x = t[c][2 * tx];
    o.y = t[c][2 * tx + 1];
    *(ushort2*)(out + (c0 + c) * (size_t)R + r0 + 2 * tx) = o;  // 256B coalesced write
  }
}

// ---------------- router ----------------
__global__ __launch_bounds__(256) void router_kernel(
    const float* __restrict__ X, const float* __restrict__ wg, const float* __restrict__ bg,
    float* __restrict__ probs, int* __restrict__ topi, float* __restrict__ gatew){
  int t = blockIdx.x;
  const float* x = X + (size_t)t * HD;
  float a0 = 0.f, a1 = 0.f, a2 = 0.f, a3 = 0.f;
  for (int h = threadIdx.x; h < HD; h += 256){
    float xv = x[h];
    float4 w = ((const float4*)wg)[h];
    a0 += xv * w.x; a1 += xv * w.y; a2 += xv * w.z; a3 += xv * w.w;
  }
  __shared__ float red[4][256];
  red[0][threadIdx.x] = a0; red[1][threadIdx.x] = a1;
  red[2][threadIdx.x] = a2; red[3][threadIdx.x] = a3;
  __syncthreads();
  for (int s = 128; s > 0; s >>= 1){
    if (threadIdx.x < (unsigned)s){
      #pragma unroll
      for (int e = 0; e < 4; e++) red[e][threadIdx.x] += red[e][threadIdx.x + s];
    }
    __syncthreads();
  }
  if (threadIdx.x == 0){
    float l[4], p[4];
    #pragma unroll
    for (int e = 0; e < 4; e++) l[e] = red[e][0] + bg[e];
    float mx = fmaxf(fmaxf(l[0], l[1]), fmaxf(l[2], l[3]));
    float s = 0.f;
    #pragma unroll
    for (int e = 0; e < 4; e++){ p[e] = expf(l[e] - mx); s += p[e]; }
    #pragma unroll
    for (int e = 0; e < 4; e++){ p[e] /= s; probs[t * 4 + e] = p[e]; }
    int e0 = 0;
    for (int e = 1; e < 4; e++) if (p[e] > p[e0]) e0 = e;
    int e1 = -1;
    for (int e = 0; e < 4; e++){ if (e == e0) continue; if (e1 < 0 || p[e] > p[e1]) e1 = e; }
    float g = p[e0] + p[e1];
    topi[t * 2] = e0; topi[t * 2 + 1] = e1;
    #pragma unroll
    for (int e = 0; e < 4; e++)
      gatew[(size_t)e * TOK + t] = (e == e0) ? p[e0] / g : (e == e1) ? p[e1] / g : 0.f;
  }
}

// ---------------- expert token lists ----------------
__global__ __launch_bounds__(256) void build_lists(const int* __restrict__ topi,
                                                   int* __restrict__ cnt,
                                                   int* __restrict__ lists){
  int t = blockIdx.x * 256 + threadIdx.x;
  if (t >= TOK) return;
  #pragma unroll
  for (int k = 0; k < 2; k++){
    int e = topi[t * 2 + k];
    int p = atomicAdd(cnt + e, 1);
    lists[e * TOK + p] = t;
  }
}

// ---------------- aux loss ----------------
__global__ __launch_bounds__(256) void aux_kernel(const float* __restrict__ probs,
                                                  const int* __restrict__ topi,
                                                  float* __restrict__ out_aux){
  __shared__ float sp[4][256];
  __shared__ float sc[4][256];
  float p[4] = {0,0,0,0}, c[4] = {0,0,0,0};
  for (int t = threadIdx.x; t < TOK; t += 256){
    #pragma unroll
    for (int e = 0; e < 4; e++) p[e] += probs[t * 4 + e];
    c[topi[t * 2]]     += 1.f;
    c[topi[t * 2 + 1]] += 1.f;
  }
  #pragma unroll
  for (int e = 0; e < 4; e++){ sp[e][threadIdx.x] = p[e]; sc[e][threadIdx.x] = c[e]; }
  __syncthreads();
  for (int s = 128; s > 0; s >>= 1){
    if (threadIdx.x < (unsigned)s){
      #pragma unroll
      for (int e = 0; e < 4; e++){
        sp[e][threadIdx.x] += sp[e][threadIdx.x + s];
        sc[e][threadIdx.x] += sc[e][threadIdx.x + s];
      }
    }
    __syncthreads();
  }
  if (threadIdx.x == 0){
    float aux = 0.f;
    #pragma unroll
    for (int e = 0; e < 4; e++)
      aux += (sc[e][0] / (float)(TOK * 2)) * (sp[e][0] / (float)TOK);
    *out_aux = 4.f * aux;
  }
}

// =====================================================================
// Unified m97-style MoE GEMM. 128x128 tile, BK=64, 256 thr (4 waves
// 2x2, wave-tile 64x64), SINGLE-buffered 32 KB LDS (5 blocks/CU).
// R12->R13: panel-chunked XCD mapping — each XCD owns a contiguous
// bx-range, iterated by-fast, so co-resident blocks in an XCD share
// a few B-panels (fits 4MB L2; each panel fetched by exactly 1 XCD).
// Requires gridDim.x % 8 == 0 (64 and 16: ok).
// EPI 0: A = Xb gathered via rowidx (clamped); Hb[row] = gelu(acc+b1)
// EPI 1: A = Hb; out[tok] += gate[tok]*(acc+b2)  (masked scatter-add)
// =====================================================================
template<int EPI, int N, int K>
__global__ __launch_bounds__(256) void gemm_97(
    const u16* __restrict__ A, const u16* __restrict__ BT,
    const int* __restrict__ rowidx, const int* __restrict__ cntp,
    const float* __restrict__ bias,
    u16* __restrict__ Hout,
    const float* __restrict__ gate, float* __restrict__ Cout)
{
  __shared__ __align__(16) u16 As[128 * 64];   // 16 KB
  __shared__ __align__(16) u16 Bs[128 * 64];   // 16 KB  (32 KB total)
  const int Mv = *cntp;
  const int gx = gridDim.x, gy = gridDim.y;
  const int orig = blockIdx.x + gx * blockIdx.y;
  const int xcd = orig & 7, rank = orig >> 3;          // nwg % 8 == 0
  const int bxl = rank / gy, by = rank % gy;           // by-fast within XCD chunk
  const int bx = xcd * (gx >> 3) + bxl;                // bijective
  const int browg = by * 128;
  if (browg >= Mv) return;
  const size_t bcol = (size_t)bx * 128;

  const int tid = threadIdx.x, lane = tid & 63, w = tid >> 6;   // 4 waves 2x2
  const int wr = w >> 1, wc = w & 1;
  const int l8 = lane >> 3;
  const int csw  = ((lane & 7) ^ l8) * 8;
  const int sw   = (lane & 7) * 8;
  const int h8   = ((lane >> 4) & 3) * 8;
  const int colk0 = h8 ^ sw, colk1 = (32 | h8) ^ sw;
  const int r16 = lane & 15;

  // B ops j=0..3: rows j*32 + w*8 + l8 (covers 128 jointly over waves)
  const u16* bsrc[4]; int bch[4];
  #pragma unroll
  for (int j = 0; j < 4; j++){
    int rb = j * 32 + w * 8;
    bch[j] = rb * 128;
    bsrc[j] = BT + (bcol + rb + l8) * (size_t)K + csw;
  }
  // A ops q=0..3: rows wr*64 + q*16 + wc*8 + l8 (covers 128 jointly)
  const u16* asrc[4]; int ach[4];
  #pragma unroll
  for (int q = 0; q < 4; q++){
    int rb = wr * 64 + q * 16 + wc * 8;
    ach[q] = rb * 128;
    int rl = browg + rb + l8;
    int ar;
    if (EPI == 0){
      if (rl > Mv - 1) rl = Mv - 1;   // clamp pad rows to a valid token
      ar = rowidx[rl];
    } else {
      ar = rl;                        // Hb expert-local row (pad rows masked at EPI)
    }
    asrc[q] = A + (size_t)ar * K + csw;
  }

  f32x4 acc[4][4];
  #pragma unroll
  for (int m = 0; m < 4; m++)
    #pragma unroll
    for (int n = 0; n < 4; n++) acc[m][n] = (f32x4){0.f, 0.f, 0.f, 0.f};
  bf16x8 bC[8];

  const int NT = K / 64;
  for (int t = 0; t < NT; ++t){
    const size_t ko = (size_t)t * 64;
    __syncthreads();                        // prev tile's ds_reads done before overwrite
    #pragma unroll
    for (int j = 0; j < 4; j++) gload_lds16(bsrc[j] + ko, (char*)Bs + bch[j]);
    #pragma unroll
    for (int q = 0; q < 4; q++) gload_lds16(asrc[q] + ko, (char*)As + ach[q]);
    __syncthreads();                        // drains vmcnt(0) before barrier

    #pragma unroll
    for (int nf = 0; nf < 4; nf++){
      const u16* bp = Bs + (wc * 64 + nf * 16 + r16) * 64;
      bC[nf * 2]     = *(const bf16x8*)(bp + colk0);
      bC[nf * 2 + 1] = *(const bf16x8*)(bp + colk1);
    }
    #pragma unroll
    for (int m = 0; m < 4; m++){
      const u16* ap = As + (wr * 64 + m * 16 + r16) * 64;
      bf16x8 a0 = *(const bf16x8*)(ap + colk0);
      bf16x8 a1 = *(const bf16x8*)(ap + colk1);
      #pragma unroll
      for (int nf = 0; nf < 4; nf++){
        acc[m][nf] = mfma_bf16(a0, bC[nf * 2],     acc[m][nf]);
        acc[m][nf] = mfma_bf16(a1, bC[nf * 2 + 1], acc[m][nf]);
      }
    }
  }

  // epilogue
  const int cl = r16, rg = (lane >> 4) * 4;
  const size_t c0 = bcol + wc * 64;
  float bv[4];
  #pragma unroll
  for (int nf = 0; nf < 4; nf++) bv[nf] = bias[c0 + nf * 16 + cl];
  #pragma unroll
  for (int mf = 0; mf < 4; mf++){
    const int rbase = browg + wr * 64 + mf * 16 + rg;
    if (EPI == 0){
      #pragma unroll
      for (int nf = 0; nf < 4; nf++){
        const size_t col = c0 + nf * 16 + cl;
        #pragma unroll
        for (int j = 0; j < 4; j++)
          Hout[(size_t)(rbase + j) * N + col] = f2bf(gelu_tanh(acc[mf][nf][j] + bv[nf]));
      }
    } else {
      int   tok[4]; float gv[4];
      #pragma unroll
      for (int j = 0; j < 4; j++){
        const bool ok = (rbase + j) < Mv;
        tok[j] = ok ? rowidx[rbase + j] : -1;
        gv[j]  = ok ? gate[tok[j]] : 0.f;
      }
      #pragma unroll
      for (int nf = 0; nf < 4; nf++){
        const size_t col = c0 + nf * 16 + cl;
        #pragma unroll
        for (int j = 0; j < 4; j++){
          if (tok[j] >= 0){
            const size_t idx = (size_t)tok[j] * N + col;
            Cout[idx] += gv[j] * (acc[mf][nf][j] + bv[nf]);  // serialized dispatches -> race-free
          }
        }
      }
    }
  }
}

// ---------------- host ----------------
extern "C" void kernel_launch(void* const* d_in, const int* in_sizes, int n_in,
                              void* d_out, int out_size, void* d_ws, size_t ws_size,
                              hipStream_t stream){
  (void)in_sizes; (void)n_in; (void)ws_size;
  const float* X  = (const float*)d_in[0];
  const float* wg = (const float*)d_in[1];
  const float* bg = (const float*)d_in[2];
  const float* w1 = (const float*)d_in[3];
  const float* b1 = (const float*)d_in[4];
  const float* w2 = (const float*)d_in[5];
  const float* b2 = (const float*)d_in[6];
  float* out = (float*)d_out;

  char* ws = (char*)d_ws;
  size_t off = 0;
  auto alloc = [&](size_t b) -> char* {
    char* p = ws + off;
    off = (off + b + 255) & ~(size_t)255;
    return p;
  };
  u16*   Xb    = (u16*)  alloc((size_t)TOK * HD * 2);
  u16*   W1T   = (u16*)  alloc((size_t)FFD * HD * 2);
  u16*   W2T   = (u16*)  alloc((size_t)HD * FFD * 2);
  float* probs = (float*)alloc((size_t)TOK * 4 * 4);
  int*   topi  = (int*)  alloc((size_t)TOK * 2 * 4);
  float* gatew = (float*)alloc((size_t)NEXP * TOK * 4);
  int*   cnt   = (int*)  alloc((size_t)NEXP * 4);
  int*   lists = (int*)  alloc((size_t)NEXP * TOK * 4);
  u16*   Hb    = (u16*)  alloc((size_t)CAPE * FFD * 2);   // 68 MB

  hipMemsetAsync(cnt, 0, NEXP * sizeof(int), stream);
  hipMemsetAsync(out, 0, (size_t)TOK * HD * sizeof(float), stream);

  cvt_to_bf16<<<(TOK * HD / 4 + 255) / 256, 256, 0, stream>>>(X, Xb, TOK * HD / 4);
  router_kernel<<<TOK, 256, 0, stream>>>(X, wg, bg, probs, topi, gatew);
  build_lists<<<TOK / 256, 256, 0, stream>>>(topi, cnt, lists);
  aux_kernel<<<1, 256, 0, stream>>>(probs, topi, out + (out_size - 1));

  for (int e = 0; e < NEXP; ++e){
    transpose_cvt<<<dim3(FFD / 64, HD / 128), 256, 0, stream>>>(
        w1 + (size_t)e * HD * FFD, W1T, HD, FFD);
    transpose_cvt<<<dim3(HD / 64, FFD / 128), 256, 0, stream>>>(
        w2 + (size_t)e * FFD * HD, W2T, FFD, HD);
    gemm_97<0, FFD, HD><<<dim3(FFD / 128, CAPE / 128), 256, 0, stream>>>(
        Xb, W1T, lists + e * TOK, cnt + e, b1 + (size_t)e * FFD,
        Hb, nullptr, nullptr);
    gemm_97<1, HD, FFD><<<dim3(HD / 128, CAPE / 128), 256, 0, stream>>>(
        Hb, W2T, lists + e * TOK, cnt + e, b2 + (size_t)e * HD,
        nullptr, gatew + (size_t)e * TOK, out);
  }
}